// Round 10
// baseline (463.524 us; speedup 1.0000x reference)
//
#include <hip/hip_runtime.h>
#include <math.h>

// SLAYER SNN forward, 6 layers, T=2048.
// Policy: compute near the TRUE value (error << reference's own fp32 noise
// ~1e-5) so binary spike decisions match the golden fp32 reference exactly.
//
// PSP = exact 2nd-order IIR of the truncated SRM kernel; refractory = 2-state
// recurrence; time-chunked speculative scan (32 chunks x 64 steps, 64-step
// warmup; init error decays e^-1/step -- proven R5-R9).
//
// DENSE1 (1600->300) as an EXACT fixed-point bf16 MFMA GEMM (R7/R9-proven):
//   w_fixed = round(w*2^45) = sum_{j<6} d_j 256^j, d_j signed 8-bit digits.
//   Digits and 0/1 spikes are exact in bf16; mfma_f32_16x16x32_bf16
//   accumulates integer partial sums < 2^24 -> EXACT in f32 C. Limb combine
//   in f64 (each term integer x 2^(8j), exact; residual ~1e-12 weight-units).
// R10: reuse-first tiling. M-tile 64 (4 waves x 16 rows, full K per wave --
//   no K-split, no LDS reduce), 32 bm x 4 ct = 128 blocks, XCD-aware ct
//   assignment so each XCD's L2 holds ONE 1.5 MB B-panel.

#define T_BINS 2048
#define K_SRM  100
#define AEXP   0.36787944117144233   // e^-1
#define CHK    64                    // chunk output length
#define WUP    64                    // refractory warmup length (proven)
#define NCHK   (T_BINS / CHK)        // 32
#define FIXS   35184372088832.0      // 2^45

typedef __attribute__((ext_vector_type(8))) short          s16x8;
typedef __attribute__((ext_vector_type(8))) unsigned short u16x8;
typedef __attribute__((ext_vector_type(4))) float          f32x4;

// ---------------- fused prep: conv1 + packB(bf16 limbs) + transposes + init -
__global__ __launch_bounds__(256) void k_prep(
    const float* __restrict__ x, const float* __restrict__ Wc1,
    const float* __restrict__ Wf1, const float* __restrict__ Wf2,
    const float* __restrict__ Wf3, float* __restrict__ c1,
    double* __restrict__ Scum, double* __restrict__ H,
    float* __restrict__ WT2, float* __restrict__ WT3,
    unsigned short* __restrict__ BL) {
  int b = blockIdx.x, tid = threadIdx.x;
  if (b < 19) {                         // ---- conv1 -> c1[4704]
    int idx = b * 256 + tid;
    if (idx >= 4704) return;
    int o = idx / 784, r = idx % 784, i = r / 28, j = r % 28;
    double acc = 0.0;
    for (int ci = 0; ci < 3; ++ci)
      for (int ky = 0; ky < 5; ++ky) {
        const float* xr = x + ci * 1024 + (i + ky) * 32 + j;
        const float* wr = Wc1 + ((o * 3 + ci) * 5 + ky) * 5;
#pragma unroll
        for (int kx = 0; kx < 5; ++kx)
          acc += (double)xr[kx] * (double)wr[kx];
      }
    c1[idx] = (float)acc;
  } else if (b < 269) {                 // ---- packB: 6 bf16 digit limbs
    int idx = (b - 19) * 256 + tid;     // 50 ks x 320 n x 4 g = 64000
    if (idx >= 64000) return;
    int g = idx & 3, rest = idx >> 2;
    int n = rest % 320, ks = rest / 320;
    u16x8 out[6];
#pragma unroll
    for (int j = 0; j < 6; ++j)
#pragma unroll
      for (int jj = 0; jj < 8; ++jj) out[j][jj] = 0;
    if (n < 300) {
      const float* wr = Wf1 + (size_t)n * 1600 + ks * 32 + g * 8;
#pragma unroll
      for (int jj = 0; jj < 8; ++jj) {
        long long v = llrint((double)wr[jj] * FIXS);
#pragma unroll
        for (int j = 0; j < 6; ++j) {
          int d = (int)(signed char)(v & 0xFF);
          v = (v - d) >> 8;
          float fd = (float)d;               // exact; bf16 truncation exact
          unsigned int fb = __float_as_uint(fd);
          out[j][jj] = (unsigned short)(fb >> 16);
        }
      }
    }
#pragma unroll
    for (int j = 0; j < 6; ++j)
      ((u16x8*)BL)[((j * 50 + ks) * 320 + n) * 4 + g] = out[j];
  } else if (b < 451) {                 // ---- WT2 / WT3 transposes
    int idx = (b - 269) * 256 + tid;
    if (idx < 45000) {
      int c = idx / 150, o = idx - c * 150;
      WT2[idx] = Wf2[o * 300 + c];
    } else if (idx < 46500) {
      int j = idx - 45000, c = j / 10, o = j - c * 10;
      WT3[j] = Wf3[o * 150 + c];
    }
  } else {                              // ---- init tables
    if (tid == 0) {
      double acc = 0.0;
      for (int k = 0; k < K_SRM; ++k) {
        double tk = (double)k;
        double h = (tk * 0.1) * exp(1.0 - tk * 0.1);
        H[k] = h; acc += h; Scum[k] = acc;
      }
      H[100] = 0.0; H[101] = 0.0;
    }
  }
}

// ---------------- layer1 chunked scan: p1[t] = c1*Scum[t] -------------------
__global__ __launch_bounds__(256) void k_scan1_chunk(
    const float* __restrict__ c1, const double* __restrict__ Scum_g,
    unsigned char* __restrict__ s1b) {
  __shared__ double Sc[K_SRM];
  for (int k = threadIdx.x; k < K_SRM; k += 256) Sc[k] = Scum_g[k];
  __syncthreads();
  int idx = blockIdx.x * 256 + threadIdx.x;
  int chunk = idx / 4704, n = idx - chunk * 4704;
  int t0 = chunk * CHK;
  int ts = (chunk == 0) ? 0 : t0 - WUP;
  double w = (double)c1[n];
  double e1 = 0.0, e2 = 0.0;
  double u = w * Sc[ts < (K_SRM - 1) ? ts : (K_SRM - 1)];
  unsigned char* outp = s1b + n;
  for (int t = ts; t < t0; ++t) {       // warmup, no store
    double s = (u >= 1.0) ? 1.0 : 0.0;
    int si = t + 1 < (K_SRM - 1) ? t + 1 : (K_SRM - 1);
    u = w * Sc[si] - 2.0 * ((e1 + e2) + s);
    double t1 = e1 + s;
    e2 = AEXP * (e2 + t1); e1 = AEXP * t1;
  }
#pragma unroll 8
  for (int t = t0; t < t0 + CHK; ++t) { // output
    double s = (u >= 1.0) ? 1.0 : 0.0;
    outp[(size_t)t * 4704] = (unsigned char)s;
    int si = t + 1 < (K_SRM - 1) ? t + 1 : (K_SRM - 1);
    u = w * Sc[si] - 2.0 * ((e1 + e2) + s);
    double t1 = e1 + s;
    e2 = AEXP * (e2 + t1); e1 = AEXP * t1;
  }
}

// ---------------- pool: 2x2 spike count -> y2b[t][1176] bytes ---------------
__global__ __launch_bounds__(256) void k_pool(const unsigned char* __restrict__ s1b,
                                              unsigned char* __restrict__ y2b) {
  int idx = blockIdx.x * blockDim.x + threadIdx.x;
  if (idx >= 1176 * T_BINS) return;
  int t = idx / 1176, n2 = idx - t * 1176;
  int c = n2 / 196, r = n2 % 196, i = r / 14, j = r % 14;
  const unsigned char* b = s1b + (size_t)t * 4704 + c * 784 + (2 * i) * 28 + 2 * j;
  y2b[idx] = (unsigned char)((int)b[0] + (int)b[1] + (int)b[28] + (int)b[29]);
}

// ---------------- chunked fused PSP(IIR) + spike scan -----------------------
template <typename Tin, typename Tout>
__global__ __launch_bounds__(256) void k_psp_scan_chunk(
    const Tin* __restrict__ z, Tout* __restrict__ sout, int N,
    long strideT, long strideN, const double* __restrict__ H_g,
    double A1, double A2, double B1, double C0, double C1, double xscale) {
  __shared__ double Hs[102];
  for (int k = threadIdx.x; k < 102; k += 256) Hs[k] = H_g[k];
  __syncthreads();
  int idx = blockIdx.x * blockDim.x + threadIdx.x;
  if (idx >= NCHK * N) return;
  int chunk = idx / N, n = idx - chunk * N;
  int t0 = chunk * CHK;
  int ts = (chunk == 0) ? 0 : t0 - WUP;
  const Tin* zn = z + n;

  // exact IIR init: accA=p[ts], accB=p[ts-1] (100-tap FIR, 10-deep pipe)
  double accA = 0.0, accB = 0.0;
  float fA[10], fB[10];
#define LOADF(BUF, J0)                                               \
  { _Pragma("unroll")                                                \
    for (int q_ = 0; q_ < 10; ++q_)                                  \
      BUF[q_] = (float)zn[(long)(ts - 1 - ((J0) + q_)) * (long)N]; }
#define FMA10(BUF, J0)                                               \
  { _Pragma("unroll")                                                \
    for (int q_ = 0; q_ < 10; ++q_) {                                \
      double v_ = (double)BUF[q_];                                   \
      accA += Hs[(J0) + q_ + 1] * v_;                                \
      accB += Hs[(J0) + q_] * v_;                                    \
    } }
  LOADF(fA, 0)
  for (int q = 0; q < 100; q += 20) {
    LOADF(fB, q + 10)
    FMA10(fA, q)
    LOADF(fA, q + 20)                  // q=80: overshoot, in-bounds, unused
    FMA10(fB, q + 10)
  }
#undef LOADF
#undef FMA10
  double pp1 = accA * xscale;          // p[ts]
  double pp2 = accB * xscale;          // p[ts-1]
  double xm100 = (double)(float)zn[(long)(ts - 100) * (long)N];
  double u = pp1, e1 = 0.0, e2 = 0.0;  // refractory speculated zero

  float cA[8], cB[8], lA[8], lB[8];
  size_t oa = (size_t)n * (size_t)strideN + (size_t)t0 * (size_t)strideT;
  int nwg = (t0 - ts) >> 3;            // 0 or 8 warmup groups
  int ngrp = nwg + CHK / 8;            // 8 or 16 (even)
#define PREF8(CBUF, LBUF, TB)                                        \
  { long tb_ = (long)(TB);                                           \
    _Pragma("unroll")                                                \
    for (int j_ = 0; j_ < 8; ++j_) {                                 \
      CBUF[j_] = (float)zn[(tb_ + j_) * (long)N];                    \
      LBUF[j_] = (float)zn[(tb_ + j_ - 99) * (long)N];               \
    } }
#define PROC8(CBUF, LBUF, DOSTORE)                                   \
  { _Pragma("unroll")                                                \
    for (int j_ = 0; j_ < 8; ++j_) {                                 \
      double s = (u >= 1.0) ? 1.0 : 0.0;                             \
      if (DOSTORE) { sout[oa] = (Tout)s; oa += (size_t)strideT; }    \
      double xt = (double)CBUF[j_], x99 = (double)LBUF[j_];          \
      double pn = A1 * pp1 - A2 * pp2 + B1 * xt - C0 * x99           \
                  + C1 * xm100;                                      \
      xm100 = x99;                                                   \
      u = pn - 2.0 * ((e1 + e2) + s);                                \
      double t1 = e1 + s;                                            \
      e2 = AEXP * (e2 + t1); e1 = AEXP * t1;                         \
      pp2 = pp1; pp1 = pn;                                           \
    } }
  PREF8(cA, lA, ts)
  for (int g = 0; g < ngrp; g += 2) {
    PREF8(cB, lB, ts + (g + 1) * 8)
    PROC8(cA, lA, g >= nwg)
    PREF8(cA, lA, ts + (g + 2) * 8)    // last iter overshoots into slack
    PROC8(cB, lB, g + 1 >= nwg)
  }
#undef PREF8
#undef PROC8
}

// ---------------- conv2: register-row-blocked, thread=(o,i) -----------------
__global__ __launch_bounds__(192) void k_conv2(const unsigned char* __restrict__ s2b,
                                               const float* __restrict__ W,
                                               float* __restrict__ z3) {
  __shared__ float ls[1176];
  __shared__ float lw[2400];
  int t = blockIdx.x;
  for (int i = threadIdx.x; i < 1176; i += 192)
    ls[i] = (float)s2b[(size_t)t * 1176 + i];
  for (int i = threadIdx.x; i < 2400; i += 192) lw[i] = W[i];
  __syncthreads();
  int tid = threadIdx.x;
  if (tid >= 160) return;
  int o = tid / 10, i = tid - o * 10;
  double acc[10];
#pragma unroll
  for (int j = 0; j < 10; ++j) acc[j] = 0.0;
  for (int ci = 0; ci < 6; ++ci)
#pragma unroll
    for (int ky = 0; ky < 5; ++ky) {
      const float* lr = &ls[ci * 196 + (i + ky) * 14];
      const float* wr = &lw[((o * 6 + ci) * 5 + ky) * 5];
      double r[14], w[5];
#pragma unroll
      for (int q = 0; q < 14; ++q) r[q] = (double)lr[q];
#pragma unroll
      for (int q = 0; q < 5; ++q) w[q] = (double)wr[q];
#pragma unroll
      for (int j = 0; j < 10; ++j)
        acc[j] += r[j] * w[0] + r[j + 1] * w[1] + r[j + 2] * w[2] +
                  r[j + 3] * w[3] + r[j + 4] * w[4];
    }
  float* zr = z3 + (size_t)t * 1600 + o * 100 + i * 10;
#pragma unroll
  for (int j = 0; j < 10; ++j) zr[j] = (float)acc[j];
}

// ---------------- dense1 bf16-limb MFMA, reuse-first tiling -----------------
// 128 blocks: xcd=bid&7, ct=xcd&3 (same 80-col B-panel per XCD -> L2-resident),
// bm=(bid>>3)+16*(xcd>>2) in 0..31 (64-row M-tile). 4 waves = 4 m-subtiles,
// each runs FULL K (50 ks): f32 C stays an exact integer (< 2^24). No K-split,
// no LDS. A-fragments built in registers from raw spike bytes.
__global__ __launch_bounds__(256) void k_mfma_dense1(
    const unsigned char* __restrict__ s3b, const unsigned short* __restrict__ BL,
    float* __restrict__ z4) {
  int bid = blockIdx.x;
  int xcd = bid & 7;
  int ct = xcd & 3;
  int bm = (bid >> 3) + ((xcd >> 2) << 4);     // 0..31
  int col0 = ct * 80;
  int w = threadIdx.x >> 6, lane = threadIdx.x & 63;
  int r = lane & 15, g = lane >> 4;
  int row = bm * 64 + w * 16 + r;
  const unsigned char* ab = s3b + (size_t)row * 1600 + g * 8;

  double za[5][4];
#pragma unroll
  for (int nt = 0; nt < 5; ++nt)
#pragma unroll
    for (int q = 0; q < 4; ++q) za[nt][q] = 0.0;
  double scale = 1.0;
  for (int j = 0; j < 6; ++j) {
    f32x4 C[5];
#pragma unroll
    for (int nt = 0; nt < 5; ++nt) C[nt] = (f32x4){0.f, 0.f, 0.f, 0.f};
    const u16x8* bj = (const u16x8*)BL + ((size_t)(j * 50 * 320 + col0 + r)) * 4 + g;
#pragma unroll 2
    for (int ks = 0; ks < 50; ++ks) {
      unsigned long long bits = *(const unsigned long long*)(ab + ks * 32);
      u16x8 f;
#pragma unroll
      for (int jj = 0; jj < 8; ++jj)
        f[jj] = ((bits >> (8 * jj)) & 1ULL) ? (unsigned short)0x3F80
                                            : (unsigned short)0;
      s16x8 a = (s16x8)f;
      const u16x8* bb = bj + (size_t)ks * 320 * 4;
#pragma unroll
      for (int nt = 0; nt < 5; ++nt)
        C[nt] = __builtin_amdgcn_mfma_f32_16x16x32_bf16(
            a, (s16x8)bb[nt * 64], C[nt], 0, 0, 0);
    }
#pragma unroll
    for (int nt = 0; nt < 5; ++nt)
#pragma unroll
      for (int q = 0; q < 4; ++q) za[nt][q] += scale * (double)C[nt][q];
    scale *= 256.0;
  }

  int row0 = bm * 64 + w * 16 + g * 4;         // D: col=lane&15, row=g*4+q
#pragma unroll
  for (int nt = 0; nt < 5; ++nt) {
    int col = col0 + nt * 16 + r;
    if (col < 300) {
#pragma unroll
      for (int q = 0; q < 4; ++q)
        z4[(size_t)(row0 + q) * 300 + col] = (float)(za[nt][q] * (1.0 / FIXS));
    }
  }
}

// ---------------- sparse dense: one output per lane -------------------------
template <int NIN, int NOUT, int BLK>
__global__ __launch_bounds__(BLK) void k_dense_sparse(
    const unsigned char* __restrict__ s, const float* __restrict__ WT,
    float* __restrict__ z) {
  constexpr int NCH = (NIN + BLK - 1) / BLK;
  constexpr int NW = BLK / 64;
  __shared__ __align__(16) int list[NIN];
  __shared__ int wcnt[NCH][NW];
  int t = blockIdx.x;
  const unsigned char* srow = s + (size_t)t * NIN;
  int tid = threadIdx.x, lane = tid & 63, wv = tid >> 6;
  unsigned long long msave[NCH];
  bool asave[NCH];
#pragma unroll
  for (int ci = 0; ci < NCH; ++ci) {
    int c = ci * BLK + tid;
    bool a = (c < NIN) && (srow[c] != 0);
    unsigned long long m = __ballot(a);
    msave[ci] = m; asave[ci] = a;
    if (lane == 0) wcnt[ci][wv] = __popcll(m);
  }
  __syncthreads();
  int nact = 0;
#pragma unroll
  for (int ci = 0; ci < NCH; ++ci) {
    int off = nact;
    for (int w = 0; w < wv; ++w) off += wcnt[ci][w];
    if (asave[ci])
      list[off + __popcll(msave[ci] & ((1ULL << lane) - 1))] = ci * BLK + tid;
    for (int w = 0; w < NW; ++w) nact += wcnt[ci][w];
  }
  __syncthreads();
  if (tid >= NOUT) return;
  const float* col = WT + tid;
  double a0 = 0.0, a1 = 0.0, a2 = 0.0, a3 = 0.0;
  int k = 0, nact4 = nact & ~3;
  for (; k < nact4; k += 4) {
    int4 l4 = *(const int4*)&list[k];
    a0 += (double)col[(size_t)l4.x * NOUT];
    a1 += (double)col[(size_t)l4.y * NOUT];
    a2 += (double)col[(size_t)l4.z * NOUT];
    a3 += (double)col[(size_t)l4.w * NOUT];
  }
  for (; k < nact; ++k) a0 += (double)col[(size_t)list[k] * NOUT];
  z[(size_t)t * NOUT + tid] = (float)((a0 + a1) + (a2 + a3));
}

// ---------------- launch ----------------------------------------------------
extern "C" void kernel_launch(void* const* d_in, const int* in_sizes, int n_in,
                              void* d_out, int out_size, void* d_ws, size_t ws_size,
                              hipStream_t stream) {
  const float* x   = (const float*)d_in[0];
  const float* Wc1 = (const float*)d_in[1];
  const float* Wc2 = (const float*)d_in[2];
  const float* Wf1 = (const float*)d_in[3];
  const float* Wf2 = (const float*)d_in[4];
  const float* Wf3 = (const float*)d_in[5];
  float* out = (float*)d_out;
  char* ws = (char*)d_ws;

  // Workspace (~39.3 MB). Zeroed pads below zA / y2b serve FIR/IIR negative-
  // row reads; slack absorbs prefetch overshoot (values unused). z4/z5/z6
  // reuse zA (z3 dead by then).
  double* Scum = (double*)(ws + 0);                   // double[100]
  double* Htab = (double*)(ws + 2048);                // double[102]
  float*  c1   = (float*)(ws + 4096);                 // float[4704]
  const size_t PADZ = 65536;                          // 655360 B zeros
  const size_t ZA   = PADZ + 655360;                  // 720896
  const size_t PADY = ZA + 13107200 + 262144;         // 14090240 (131072 zeros)
  const size_t Y2B  = PADY + 131072;                  // 14221312
  const size_t S1B  = Y2B + 2408448 + 65536;          // 16695296
  const size_t S2B  = S1B + 9633792;                  // 26329088
  const size_t S3B  = S2B + 2408448;                  // 28737536
  const size_t S4B  = S3B + 3276800;                  // 32014336
  const size_t S5B  = S4B + 614400;                   // 32628736
  const size_t WB   = S5B + 307200;                   // 32935936 WT2
  const size_t WC   = WB + 180000;                    // 33115936 WT3
  const size_t BLa  = 33122000;                       // BL: 6,144,000 (16-al.)
  float* zA = (float*)(ws + ZA);
  unsigned char* y2b = (unsigned char*)(ws + Y2B);
  unsigned char* s1b = (unsigned char*)(ws + S1B);
  unsigned char* s2b = (unsigned char*)(ws + S2B);
  unsigned char* s3b = (unsigned char*)(ws + S3B);
  unsigned char* s4b = (unsigned char*)(ws + S4B);
  unsigned char* s5b = (unsigned char*)(ws + S5B);
  float* WT2 = (float*)(ws + WB);
  float* WT3 = (float*)(ws + WC);
  unsigned short* BLp = (unsigned short*)(ws + BLa);

  // IIR coefficients (host, double): h[k] = c*k*b^k, truncated at K=100.
  double b = exp(-0.1), c = 0.1 * exp(1.0);
  double A1 = 2.0 * b, A2 = b * b;
  double B1 = c * b;
  double C0 = 100.0 * c * pow(b, 100.0);
  double C1 = 99.0 * c * pow(b, 101.0);
  double sc = (double)1.1f;                  // pool weight, exact fp32 value

  hipMemsetAsync(ws + PADZ, 0, 655360, stream);
  hipMemsetAsync(ws + PADY, 0, 131072, stream);
  k_prep<<<452, 256, 0, stream>>>(x, Wc1, Wf1, Wf2, Wf3, c1, Scum, Htab,
                                  WT2, WT3, BLp);
  k_scan1_chunk<<<NCHK * 4704 / 256, 256, 0, stream>>>(c1, Scum, s1b);
  k_pool<<<(1176 * T_BINS) / 256, 256, 0, stream>>>(s1b, y2b);
  k_psp_scan_chunk<unsigned char, unsigned char>
      <<<(NCHK * 1176 + 255) / 256, 256, 0, stream>>>(
      y2b, s2b, 1176, 1176L, 1L, Htab, A1, A2, B1 * sc, C0 * sc, C1 * sc, sc);
  k_conv2<<<T_BINS, 192, 0, stream>>>(s2b, Wc2, zA);
  k_psp_scan_chunk<float, unsigned char>
      <<<(NCHK * 1600 + 255) / 256, 256, 0, stream>>>(
      zA, s3b, 1600, 1600L, 1L, Htab, A1, A2, B1, C0, C1, 1.0);
  k_mfma_dense1<<<128, 256, 0, stream>>>(s3b, BLp, zA);
  k_psp_scan_chunk<float, unsigned char>
      <<<(NCHK * 300 + 255) / 256, 256, 0, stream>>>(
      zA, s4b, 300, 300L, 1L, Htab, A1, A2, B1, C0, C1, 1.0);
  k_dense_sparse<300, 150, 192><<<T_BINS, 192, 0, stream>>>(s4b, WT2, zA);
  k_psp_scan_chunk<float, unsigned char>
      <<<(NCHK * 150 + 255) / 256, 256, 0, stream>>>(
      zA, s5b, 150, 150L, 1L, Htab, A1, A2, B1, C0, C1, 1.0);
  k_dense_sparse<150, 10, 64><<<T_BINS, 64, 0, stream>>>(s5b, WT3, zA);
  k_psp_scan_chunk<float, float><<<2, 256, 0, stream>>>(
      zA, out, 10, 1L, 2048L, Htab, A1, A2, B1, C0, C1, 1.0);

  (void)in_sizes; (void)n_in; (void)out_size; (void)ws_size;
}

// Round 11
// 379.976 us; speedup vs baseline: 1.2199x; 1.2199x over previous
//
#include <hip/hip_runtime.h>
#include <math.h>

// SLAYER SNN forward, 6 layers, T=2048.
// Policy: compute near the TRUE value (error << reference's own fp32 noise
// ~1e-5) so binary spike decisions match the golden fp32 reference exactly.
//
// PSP = exact 2nd-order IIR of the truncated SRM kernel; refractory = 2-state
// recurrence; time-chunked speculative scan (32 chunks x 64 steps, 64-step
// warmup; init error decays e^-1/step -- proven R5-R10).
//
// DENSE1 (1600->300) as an EXACT fixed-point bf16 MFMA GEMM (R7/R9/R10-proven
// math): w_fixed = round(w*2^45) = sum_{j<6} d_j 256^j, d_j signed 8-bit
// digits. Digits and 0/1 spikes are exact in bf16; mfma_f32_16x16x32_bf16
// accumulates integer partial sums < 2^24 -> EXACT in f32 C. Limb combine in
// f64 (each term integer x 2^(8j), exact).
// R11: ks-outer / j-inner with ALL 30 accumulators live (C[6][5], 120 VGPR)
//   -> ~30 independent load->MFMA chains per wave (was ~2 in R10).
//   512 single-wave blocks (128 bm x 4 ct), XCD-aware ct so each XCD's L2
//   holds ONE 1.5 MB B-panel (keeps R10's 5x FETCH reduction).

#define T_BINS 2048
#define K_SRM  100
#define AEXP   0.36787944117144233   // e^-1
#define CHK    64                    // chunk output length
#define WUP    64                    // refractory warmup length (proven)
#define NCHK   (T_BINS / CHK)        // 32
#define FIXS   35184372088832.0      // 2^45

typedef __attribute__((ext_vector_type(8))) short          s16x8;
typedef __attribute__((ext_vector_type(8))) unsigned short u16x8;
typedef __attribute__((ext_vector_type(4))) float          f32x4;

// ---------------- fused prep: conv1 + packB(bf16 limbs) + transposes + init -
__global__ __launch_bounds__(256) void k_prep(
    const float* __restrict__ x, const float* __restrict__ Wc1,
    const float* __restrict__ Wf1, const float* __restrict__ Wf2,
    const float* __restrict__ Wf3, float* __restrict__ c1,
    double* __restrict__ Scum, double* __restrict__ H,
    float* __restrict__ WT2, float* __restrict__ WT3,
    unsigned short* __restrict__ BL) {
  int b = blockIdx.x, tid = threadIdx.x;
  if (b < 19) {                         // ---- conv1 -> c1[4704]
    int idx = b * 256 + tid;
    if (idx >= 4704) return;
    int o = idx / 784, r = idx % 784, i = r / 28, j = r % 28;
    double acc = 0.0;
    for (int ci = 0; ci < 3; ++ci)
      for (int ky = 0; ky < 5; ++ky) {
        const float* xr = x + ci * 1024 + (i + ky) * 32 + j;
        const float* wr = Wc1 + ((o * 3 + ci) * 5 + ky) * 5;
#pragma unroll
        for (int kx = 0; kx < 5; ++kx)
          acc += (double)xr[kx] * (double)wr[kx];
      }
    c1[idx] = (float)acc;
  } else if (b < 269) {                 // ---- packB: 6 bf16 digit limbs
    int idx = (b - 19) * 256 + tid;     // 50 ks x 320 n x 4 g = 64000
    if (idx >= 64000) return;
    int g = idx & 3, rest = idx >> 2;
    int n = rest % 320, ks = rest / 320;
    u16x8 out[6];
#pragma unroll
    for (int j = 0; j < 6; ++j)
#pragma unroll
      for (int jj = 0; jj < 8; ++jj) out[j][jj] = 0;
    if (n < 300) {
      const float* wr = Wf1 + (size_t)n * 1600 + ks * 32 + g * 8;
#pragma unroll
      for (int jj = 0; jj < 8; ++jj) {
        long long v = llrint((double)wr[jj] * FIXS);
#pragma unroll
        for (int j = 0; j < 6; ++j) {
          int d = (int)(signed char)(v & 0xFF);
          v = (v - d) >> 8;
          float fd = (float)d;               // exact; bf16 truncation exact
          unsigned int fb = __float_as_uint(fd);
          out[j][jj] = (unsigned short)(fb >> 16);
        }
      }
    }
#pragma unroll
    for (int j = 0; j < 6; ++j)
      ((u16x8*)BL)[((j * 50 + ks) * 320 + n) * 4 + g] = out[j];
  } else if (b < 451) {                 // ---- WT2 / WT3 transposes
    int idx = (b - 269) * 256 + tid;
    if (idx < 45000) {
      int c = idx / 150, o = idx - c * 150;
      WT2[idx] = Wf2[o * 300 + c];
    } else if (idx < 46500) {
      int j = idx - 45000, c = j / 10, o = j - c * 10;
      WT3[j] = Wf3[o * 150 + c];
    }
  } else {                              // ---- init tables
    if (tid == 0) {
      double acc = 0.0;
      for (int k = 0; k < K_SRM; ++k) {
        double tk = (double)k;
        double h = (tk * 0.1) * exp(1.0 - tk * 0.1);
        H[k] = h; acc += h; Scum[k] = acc;
      }
      H[100] = 0.0; H[101] = 0.0;
    }
  }
}

// ---------------- layer1 chunked scan: p1[t] = c1*Scum[t] -------------------
__global__ __launch_bounds__(256) void k_scan1_chunk(
    const float* __restrict__ c1, const double* __restrict__ Scum_g,
    unsigned char* __restrict__ s1b) {
  __shared__ double Sc[K_SRM];
  for (int k = threadIdx.x; k < K_SRM; k += 256) Sc[k] = Scum_g[k];
  __syncthreads();
  int idx = blockIdx.x * 256 + threadIdx.x;
  int chunk = idx / 4704, n = idx - chunk * 4704;
  int t0 = chunk * CHK;
  int ts = (chunk == 0) ? 0 : t0 - WUP;
  double w = (double)c1[n];
  double e1 = 0.0, e2 = 0.0;
  double u = w * Sc[ts < (K_SRM - 1) ? ts : (K_SRM - 1)];
  unsigned char* outp = s1b + n;
  for (int t = ts; t < t0; ++t) {       // warmup, no store
    double s = (u >= 1.0) ? 1.0 : 0.0;
    int si = t + 1 < (K_SRM - 1) ? t + 1 : (K_SRM - 1);
    u = w * Sc[si] - 2.0 * ((e1 + e2) + s);
    double t1 = e1 + s;
    e2 = AEXP * (e2 + t1); e1 = AEXP * t1;
  }
#pragma unroll 8
  for (int t = t0; t < t0 + CHK; ++t) { // output
    double s = (u >= 1.0) ? 1.0 : 0.0;
    outp[(size_t)t * 4704] = (unsigned char)s;
    int si = t + 1 < (K_SRM - 1) ? t + 1 : (K_SRM - 1);
    u = w * Sc[si] - 2.0 * ((e1 + e2) + s);
    double t1 = e1 + s;
    e2 = AEXP * (e2 + t1); e1 = AEXP * t1;
  }
}

// ---------------- pool: 2x2 spike count -> y2b[t][1176] bytes ---------------
__global__ __launch_bounds__(256) void k_pool(const unsigned char* __restrict__ s1b,
                                              unsigned char* __restrict__ y2b) {
  int idx = blockIdx.x * blockDim.x + threadIdx.x;
  if (idx >= 1176 * T_BINS) return;
  int t = idx / 1176, n2 = idx - t * 1176;
  int c = n2 / 196, r = n2 % 196, i = r / 14, j = r % 14;
  const unsigned char* b = s1b + (size_t)t * 4704 + c * 784 + (2 * i) * 28 + 2 * j;
  y2b[idx] = (unsigned char)((int)b[0] + (int)b[1] + (int)b[28] + (int)b[29]);
}

// ---------------- chunked fused PSP(IIR) + spike scan -----------------------
template <typename Tin, typename Tout>
__global__ __launch_bounds__(256) void k_psp_scan_chunk(
    const Tin* __restrict__ z, Tout* __restrict__ sout, int N,
    long strideT, long strideN, const double* __restrict__ H_g,
    double A1, double A2, double B1, double C0, double C1, double xscale) {
  __shared__ double Hs[102];
  for (int k = threadIdx.x; k < 102; k += 256) Hs[k] = H_g[k];
  __syncthreads();
  int idx = blockIdx.x * blockDim.x + threadIdx.x;
  if (idx >= NCHK * N) return;
  int chunk = idx / N, n = idx - chunk * N;
  int t0 = chunk * CHK;
  int ts = (chunk == 0) ? 0 : t0 - WUP;
  const Tin* zn = z + n;

  // exact IIR init: accA=p[ts], accB=p[ts-1] (100-tap FIR, 10-deep pipe)
  double accA = 0.0, accB = 0.0;
  float fA[10], fB[10];
#define LOADF(BUF, J0)                                               \
  { _Pragma("unroll")                                                \
    for (int q_ = 0; q_ < 10; ++q_)                                  \
      BUF[q_] = (float)zn[(long)(ts - 1 - ((J0) + q_)) * (long)N]; }
#define FMA10(BUF, J0)                                               \
  { _Pragma("unroll")                                                \
    for (int q_ = 0; q_ < 10; ++q_) {                                \
      double v_ = (double)BUF[q_];                                   \
      accA += Hs[(J0) + q_ + 1] * v_;                                \
      accB += Hs[(J0) + q_] * v_;                                    \
    } }
  LOADF(fA, 0)
  for (int q = 0; q < 100; q += 20) {
    LOADF(fB, q + 10)
    FMA10(fA, q)
    LOADF(fA, q + 20)                  // q=80: overshoot, in-bounds, unused
    FMA10(fB, q + 10)
  }
#undef LOADF
#undef FMA10
  double pp1 = accA * xscale;          // p[ts]
  double pp2 = accB * xscale;          // p[ts-1]
  double xm100 = (double)(float)zn[(long)(ts - 100) * (long)N];
  double u = pp1, e1 = 0.0, e2 = 0.0;  // refractory speculated zero

  float cA[8], cB[8], lA[8], lB[8];
  size_t oa = (size_t)n * (size_t)strideN + (size_t)t0 * (size_t)strideT;
  int nwg = (t0 - ts) >> 3;            // 0 or 8 warmup groups
  int ngrp = nwg + CHK / 8;            // 8 or 16 (even)
#define PREF8(CBUF, LBUF, TB)                                        \
  { long tb_ = (long)(TB);                                           \
    _Pragma("unroll")                                                \
    for (int j_ = 0; j_ < 8; ++j_) {                                 \
      CBUF[j_] = (float)zn[(tb_ + j_) * (long)N];                    \
      LBUF[j_] = (float)zn[(tb_ + j_ - 99) * (long)N];               \
    } }
#define PROC8(CBUF, LBUF, DOSTORE)                                   \
  { _Pragma("unroll")                                                \
    for (int j_ = 0; j_ < 8; ++j_) {                                 \
      double s = (u >= 1.0) ? 1.0 : 0.0;                             \
      if (DOSTORE) { sout[oa] = (Tout)s; oa += (size_t)strideT; }    \
      double xt = (double)CBUF[j_], x99 = (double)LBUF[j_];          \
      double pn = A1 * pp1 - A2 * pp2 + B1 * xt - C0 * x99           \
                  + C1 * xm100;                                      \
      xm100 = x99;                                                   \
      u = pn - 2.0 * ((e1 + e2) + s);                                \
      double t1 = e1 + s;                                            \
      e2 = AEXP * (e2 + t1); e1 = AEXP * t1;                         \
      pp2 = pp1; pp1 = pn;                                           \
    } }
  PREF8(cA, lA, ts)
  for (int g = 0; g < ngrp; g += 2) {
    PREF8(cB, lB, ts + (g + 1) * 8)
    PROC8(cA, lA, g >= nwg)
    PREF8(cA, lA, ts + (g + 2) * 8)    // last iter overshoots into slack
    PROC8(cB, lB, g + 1 >= nwg)
  }
#undef PREF8
#undef PROC8
}

// ---------------- conv2: register-row-blocked, thread=(o,i) -----------------
__global__ __launch_bounds__(192) void k_conv2(const unsigned char* __restrict__ s2b,
                                               const float* __restrict__ W,
                                               float* __restrict__ z3) {
  __shared__ float ls[1176];
  __shared__ float lw[2400];
  int t = blockIdx.x;
  for (int i = threadIdx.x; i < 1176; i += 192)
    ls[i] = (float)s2b[(size_t)t * 1176 + i];
  for (int i = threadIdx.x; i < 2400; i += 192) lw[i] = W[i];
  __syncthreads();
  int tid = threadIdx.x;
  if (tid >= 160) return;
  int o = tid / 10, i = tid - o * 10;
  double acc[10];
#pragma unroll
  for (int j = 0; j < 10; ++j) acc[j] = 0.0;
  for (int ci = 0; ci < 6; ++ci)
#pragma unroll
    for (int ky = 0; ky < 5; ++ky) {
      const float* lr = &ls[ci * 196 + (i + ky) * 14];
      const float* wr = &lw[((o * 6 + ci) * 5 + ky) * 5];
      double r[14], w[5];
#pragma unroll
      for (int q = 0; q < 14; ++q) r[q] = (double)lr[q];
#pragma unroll
      for (int q = 0; q < 5; ++q) w[q] = (double)wr[q];
#pragma unroll
      for (int j = 0; j < 10; ++j)
        acc[j] += r[j] * w[0] + r[j + 1] * w[1] + r[j + 2] * w[2] +
                  r[j + 3] * w[3] + r[j + 4] * w[4];
    }
  float* zr = z3 + (size_t)t * 1600 + o * 100 + i * 10;
#pragma unroll
  for (int j = 0; j < 10; ++j) zr[j] = (float)acc[j];
}

// ---------------- dense1 bf16-limb MFMA: ks-outer, 30 live accumulators -----
// 512 single-wave blocks: xcd=bid&7, ct=xcd&3 (one 1.5MB B-panel per XCD L2),
// bm=(bid>>3)|((xcd>>2)<<6) in 0..127 (16-row tile). Per ks: 1 A-load + 30
// independent B-load->MFMA chains (C[6][5] exact integers < 2^24 end-to-end).
__global__ __launch_bounds__(64) void k_mfma_dense1(
    const unsigned char* __restrict__ s3b, const unsigned short* __restrict__ BL,
    float* __restrict__ z4) {
  int bid = blockIdx.x;
  int xcd = bid & 7;
  int ct = xcd & 3;
  int bm = (bid >> 3) | ((xcd >> 2) << 6);   // 0..127
  int col0 = ct * 80;
  int lane = threadIdx.x & 63;
  int r = lane & 15, g = lane >> 4;
  int row = bm * 16 + r;
  const unsigned char* ab = s3b + (size_t)row * 1600 + g * 8;

  f32x4 C[6][5];
#pragma unroll
  for (int j = 0; j < 6; ++j)
#pragma unroll
    for (int nt = 0; nt < 5; ++nt) C[j][nt] = (f32x4){0.f, 0.f, 0.f, 0.f};

  for (int ks = 0; ks < 50; ++ks) {
    unsigned long long bits = *(const unsigned long long*)(ab + ks * 32);
    u16x8 f;
#pragma unroll
    for (int jj = 0; jj < 8; ++jj)
      f[jj] = ((bits >> (8 * jj)) & 1ULL) ? (unsigned short)0x3F80
                                          : (unsigned short)0;
    s16x8 a = (s16x8)f;
    const u16x8* bks = (const u16x8*)BL + ((size_t)(ks * 320 + col0 + r)) * 4 + g;
#pragma unroll
    for (int j = 0; j < 6; ++j) {
      const u16x8* bb = bks + (size_t)j * (50 * 320 * 4);
#pragma unroll
      for (int nt = 0; nt < 5; ++nt)
        C[j][nt] = __builtin_amdgcn_mfma_f32_16x16x32_bf16(
            a, (s16x8)bb[nt * 64], C[j][nt], 0, 0, 0);
    }
  }

  int row0 = bm * 16 + g * 4;                // D: col=lane&15, row=g*4+q
#pragma unroll
  for (int nt = 0; nt < 5; ++nt) {
    int col = col0 + nt * 16 + r;
    if (col < 300) {
#pragma unroll
      for (int q = 0; q < 4; ++q) {
        double acc = 0.0, sc2 = 1.0;
#pragma unroll
        for (int j = 0; j < 6; ++j) {        // each term exact; order-free
          acc += sc2 * (double)C[j][nt][q];
          sc2 *= 256.0;
        }
        z4[(size_t)(row0 + q) * 300 + col] = (float)(acc * (1.0 / FIXS));
      }
    }
  }
}

// ---------------- sparse dense: one output per lane -------------------------
template <int NIN, int NOUT, int BLK>
__global__ __launch_bounds__(BLK) void k_dense_sparse(
    const unsigned char* __restrict__ s, const float* __restrict__ WT,
    float* __restrict__ z) {
  constexpr int NCH = (NIN + BLK - 1) / BLK;
  constexpr int NW = BLK / 64;
  __shared__ __align__(16) int list[NIN];
  __shared__ int wcnt[NCH][NW];
  int t = blockIdx.x;
  const unsigned char* srow = s + (size_t)t * NIN;
  int tid = threadIdx.x, lane = tid & 63, wv = tid >> 6;
  unsigned long long msave[NCH];
  bool asave[NCH];
#pragma unroll
  for (int ci = 0; ci < NCH; ++ci) {
    int c = ci * BLK + tid;
    bool a = (c < NIN) && (srow[c] != 0);
    unsigned long long m = __ballot(a);
    msave[ci] = m; asave[ci] = a;
    if (lane == 0) wcnt[ci][wv] = __popcll(m);
  }
  __syncthreads();
  int nact = 0;
#pragma unroll
  for (int ci = 0; ci < NCH; ++ci) {
    int off = nact;
    for (int w = 0; w < wv; ++w) off += wcnt[ci][w];
    if (asave[ci])
      list[off + __popcll(msave[ci] & ((1ULL << lane) - 1))] = ci * BLK + tid;
    for (int w = 0; w < NW; ++w) nact += wcnt[ci][w];
  }
  __syncthreads();
  if (tid >= NOUT) return;
  const float* col = WT + tid;
  double a0 = 0.0, a1 = 0.0, a2 = 0.0, a3 = 0.0;
  int k = 0, nact4 = nact & ~3;
  for (; k < nact4; k += 4) {
    int4 l4 = *(const int4*)&list[k];
    a0 += (double)col[(size_t)l4.x * NOUT];
    a1 += (double)col[(size_t)l4.y * NOUT];
    a2 += (double)col[(size_t)l4.z * NOUT];
    a3 += (double)col[(size_t)l4.w * NOUT];
  }
  for (; k < nact; ++k) a0 += (double)col[(size_t)list[k] * NOUT];
  z[(size_t)t * NOUT + tid] = (float)((a0 + a1) + (a2 + a3));
}

// ---------------- launch ----------------------------------------------------
extern "C" void kernel_launch(void* const* d_in, const int* in_sizes, int n_in,
                              void* d_out, int out_size, void* d_ws, size_t ws_size,
                              hipStream_t stream) {
  const float* x   = (const float*)d_in[0];
  const float* Wc1 = (const float*)d_in[1];
  const float* Wc2 = (const float*)d_in[2];
  const float* Wf1 = (const float*)d_in[3];
  const float* Wf2 = (const float*)d_in[4];
  const float* Wf3 = (const float*)d_in[5];
  float* out = (float*)d_out;
  char* ws = (char*)d_ws;

  // Workspace (~39.3 MB). Zeroed pads below zA / y2b serve FIR/IIR negative-
  // row reads; slack absorbs prefetch overshoot (values unused). z4/z5/z6
  // reuse zA (z3 dead by then).
  double* Scum = (double*)(ws + 0);                   // double[100]
  double* Htab = (double*)(ws + 2048);                // double[102]
  float*  c1   = (float*)(ws + 4096);                 // float[4704]
  const size_t PADZ = 65536;                          // 655360 B zeros
  const size_t ZA   = PADZ + 655360;                  // 720896
  const size_t PADY = ZA + 13107200 + 262144;         // 14090240 (131072 zeros)
  const size_t Y2B  = PADY + 131072;                  // 14221312
  const size_t S1B  = Y2B + 2408448 + 65536;          // 16695296
  const size_t S2B  = S1B + 9633792;                  // 26329088
  const size_t S3B  = S2B + 2408448;                  // 28737536
  const size_t S4B  = S3B + 3276800;                  // 32014336
  const size_t S5B  = S4B + 614400;                   // 32628736
  const size_t WB   = S5B + 307200;                   // 32935936 WT2
  const size_t WC   = WB + 180000;                    // 33115936 WT3
  const size_t BLa  = 33122000;                       // BL: 6,144,000 (16-al.)
  float* zA = (float*)(ws + ZA);
  unsigned char* y2b = (unsigned char*)(ws + Y2B);
  unsigned char* s1b = (unsigned char*)(ws + S1B);
  unsigned char* s2b = (unsigned char*)(ws + S2B);
  unsigned char* s3b = (unsigned char*)(ws + S3B);
  unsigned char* s4b = (unsigned char*)(ws + S4B);
  unsigned char* s5b = (unsigned char*)(ws + S5B);
  float* WT2 = (float*)(ws + WB);
  float* WT3 = (float*)(ws + WC);
  unsigned short* BLp = (unsigned short*)(ws + BLa);

  // IIR coefficients (host, double): h[k] = c*k*b^k, truncated at K=100.
  double b = exp(-0.1), c = 0.1 * exp(1.0);
  double A1 = 2.0 * b, A2 = b * b;
  double B1 = c * b;
  double C0 = 100.0 * c * pow(b, 100.0);
  double C1 = 99.0 * c * pow(b, 101.0);
  double sc = (double)1.1f;                  // pool weight, exact fp32 value

  hipMemsetAsync(ws + PADZ, 0, 655360, stream);
  hipMemsetAsync(ws + PADY, 0, 131072, stream);
  k_prep<<<452, 256, 0, stream>>>(x, Wc1, Wf1, Wf2, Wf3, c1, Scum, Htab,
                                  WT2, WT3, BLp);
  k_scan1_chunk<<<NCHK * 4704 / 256, 256, 0, stream>>>(c1, Scum, s1b);
  k_pool<<<(1176 * T_BINS) / 256, 256, 0, stream>>>(s1b, y2b);
  k_psp_scan_chunk<unsigned char, unsigned char>
      <<<(NCHK * 1176 + 255) / 256, 256, 0, stream>>>(
      y2b, s2b, 1176, 1176L, 1L, Htab, A1, A2, B1 * sc, C0 * sc, C1 * sc, sc);
  k_conv2<<<T_BINS, 192, 0, stream>>>(s2b, Wc2, zA);
  k_psp_scan_chunk<float, unsigned char>
      <<<(NCHK * 1600 + 255) / 256, 256, 0, stream>>>(
      zA, s3b, 1600, 1600L, 1L, Htab, A1, A2, B1, C0, C1, 1.0);
  k_mfma_dense1<<<512, 64, 0, stream>>>(s3b, BLp, zA);
  k_psp_scan_chunk<float, unsigned char>
      <<<(NCHK * 300 + 255) / 256, 256, 0, stream>>>(
      zA, s4b, 300, 300L, 1L, Htab, A1, A2, B1, C0, C1, 1.0);
  k_dense_sparse<300, 150, 192><<<T_BINS, 192, 0, stream>>>(s4b, WT2, zA);
  k_psp_scan_chunk<float, unsigned char>
      <<<(NCHK * 150 + 255) / 256, 256, 0, stream>>>(
      zA, s5b, 150, 150L, 1L, Htab, A1, A2, B1, C0, C1, 1.0);
  k_dense_sparse<150, 10, 64><<<T_BINS, 64, 0, stream>>>(s5b, WT3, zA);
  k_psp_scan_chunk<float, float><<<2, 256, 0, stream>>>(
      zA, out, 10, 1L, 2048L, Htab, A1, A2, B1, C0, C1, 1.0);

  (void)in_sizes; (void)n_in; (void)out_size; (void)ws_size;
}

// Round 12
// 269.861 us; speedup vs baseline: 1.7176x; 1.4080x over previous
//
#include <hip/hip_runtime.h>
#include <math.h>

// SLAYER SNN forward, 6 layers, T=2048.
// Policy: compute near the TRUE value (error << reference's own fp32 noise
// ~1e-5) so binary spike decisions match the golden fp32 reference exactly.
//
// PSP = exact 2nd-order IIR of the truncated SRM kernel; refractory = 2-state
// recurrence; time-chunked speculative scan (32 chunks x 64 steps, 64-step
// warmup; init error decays e^-1/step -- proven R5-R11).
//
// DENSE1 (1600->300) as an EXACT fixed-point bf16 MFMA GEMM (R7/R9-proven):
//   w_fixed = round(w*2^45) = sum_{j<6} d_j 256^j, d_j signed 8-bit digits.
//   Digits and 0/1 spikes are exact in bf16; mfma_f32_16x16x32_bf16
//   accumulates integer partial sums < 2^24 -> EXACT in f32 C. Limb combine
//   in f64 (each term integer x 2^(8j), exact).
// R12 = R9's proven kernel (4 waves/block, K-split 13/13/12/12, LDS f64
//   reduce -- latency-healthy at 2048 waves) + R10/R11's XCD-pinned panel
//   mapping ct=(bid&7)&3 (FETCH 68.8 -> 12.6 MB, proven). Single-variable
//   change from two passing configurations.

#define T_BINS 2048
#define K_SRM  100
#define AEXP   0.36787944117144233   // e^-1
#define CHK    64                    // chunk output length
#define WUP    64                    // refractory warmup length (proven)
#define NCHK   (T_BINS / CHK)        // 32
#define FIXS   35184372088832.0      // 2^45

typedef __attribute__((ext_vector_type(8))) short          s16x8;
typedef __attribute__((ext_vector_type(8))) unsigned short u16x8;
typedef __attribute__((ext_vector_type(4))) float          f32x4;

// ---------------- fused prep: conv1 + packB(bf16 limbs) + transposes + init -
__global__ __launch_bounds__(256) void k_prep(
    const float* __restrict__ x, const float* __restrict__ Wc1,
    const float* __restrict__ Wf1, const float* __restrict__ Wf2,
    const float* __restrict__ Wf3, float* __restrict__ c1,
    double* __restrict__ Scum, double* __restrict__ H,
    float* __restrict__ WT2, float* __restrict__ WT3,
    unsigned short* __restrict__ BL) {
  int b = blockIdx.x, tid = threadIdx.x;
  if (b < 19) {                         // ---- conv1 -> c1[4704]
    int idx = b * 256 + tid;
    if (idx >= 4704) return;
    int o = idx / 784, r = idx % 784, i = r / 28, j = r % 28;
    double acc = 0.0;
    for (int ci = 0; ci < 3; ++ci)
      for (int ky = 0; ky < 5; ++ky) {
        const float* xr = x + ci * 1024 + (i + ky) * 32 + j;
        const float* wr = Wc1 + ((o * 3 + ci) * 5 + ky) * 5;
#pragma unroll
        for (int kx = 0; kx < 5; ++kx)
          acc += (double)xr[kx] * (double)wr[kx];
      }
    c1[idx] = (float)acc;
  } else if (b < 269) {                 // ---- packB: 6 bf16 digit limbs
    int idx = (b - 19) * 256 + tid;     // 50 ks x 320 n x 4 g = 64000
    if (idx >= 64000) return;
    int g = idx & 3, rest = idx >> 2;
    int n = rest % 320, ks = rest / 320;
    u16x8 out[6];
#pragma unroll
    for (int j = 0; j < 6; ++j)
#pragma unroll
      for (int jj = 0; jj < 8; ++jj) out[j][jj] = 0;
    if (n < 300) {
      const float* wr = Wf1 + (size_t)n * 1600 + ks * 32 + g * 8;
#pragma unroll
      for (int jj = 0; jj < 8; ++jj) {
        long long v = llrint((double)wr[jj] * FIXS);
#pragma unroll
        for (int j = 0; j < 6; ++j) {
          int d = (int)(signed char)(v & 0xFF);
          v = (v - d) >> 8;
          float fd = (float)d;               // exact; bf16 truncation exact
          unsigned int fb = __float_as_uint(fd);
          out[j][jj] = (unsigned short)(fb >> 16);
        }
      }
    }
#pragma unroll
    for (int j = 0; j < 6; ++j)
      ((u16x8*)BL)[((j * 50 + ks) * 320 + n) * 4 + g] = out[j];
  } else if (b < 451) {                 // ---- WT2 / WT3 transposes
    int idx = (b - 269) * 256 + tid;
    if (idx < 45000) {
      int c = idx / 150, o = idx - c * 150;
      WT2[idx] = Wf2[o * 300 + c];
    } else if (idx < 46500) {
      int j = idx - 45000, c = j / 10, o = j - c * 10;
      WT3[j] = Wf3[o * 150 + c];
    }
  } else {                              // ---- init tables
    if (tid == 0) {
      double acc = 0.0;
      for (int k = 0; k < K_SRM; ++k) {
        double tk = (double)k;
        double h = (tk * 0.1) * exp(1.0 - tk * 0.1);
        H[k] = h; acc += h; Scum[k] = acc;
      }
      H[100] = 0.0; H[101] = 0.0;
    }
  }
}

// ---------------- layer1 chunked scan: p1[t] = c1*Scum[t] -------------------
__global__ __launch_bounds__(256) void k_scan1_chunk(
    const float* __restrict__ c1, const double* __restrict__ Scum_g,
    unsigned char* __restrict__ s1b) {
  __shared__ double Sc[K_SRM];
  for (int k = threadIdx.x; k < K_SRM; k += 256) Sc[k] = Scum_g[k];
  __syncthreads();
  int idx = blockIdx.x * 256 + threadIdx.x;
  int chunk = idx / 4704, n = idx - chunk * 4704;
  int t0 = chunk * CHK;
  int ts = (chunk == 0) ? 0 : t0 - WUP;
  double w = (double)c1[n];
  double e1 = 0.0, e2 = 0.0;
  double u = w * Sc[ts < (K_SRM - 1) ? ts : (K_SRM - 1)];
  unsigned char* outp = s1b + n;
  for (int t = ts; t < t0; ++t) {       // warmup, no store
    double s = (u >= 1.0) ? 1.0 : 0.0;
    int si = t + 1 < (K_SRM - 1) ? t + 1 : (K_SRM - 1);
    u = w * Sc[si] - 2.0 * ((e1 + e2) + s);
    double t1 = e1 + s;
    e2 = AEXP * (e2 + t1); e1 = AEXP * t1;
  }
#pragma unroll 8
  for (int t = t0; t < t0 + CHK; ++t) { // output
    double s = (u >= 1.0) ? 1.0 : 0.0;
    outp[(size_t)t * 4704] = (unsigned char)s;
    int si = t + 1 < (K_SRM - 1) ? t + 1 : (K_SRM - 1);
    u = w * Sc[si] - 2.0 * ((e1 + e2) + s);
    double t1 = e1 + s;
    e2 = AEXP * (e2 + t1); e1 = AEXP * t1;
  }
}

// ---------------- pool: 2x2 spike count -> y2b[t][1176] bytes ---------------
__global__ __launch_bounds__(256) void k_pool(const unsigned char* __restrict__ s1b,
                                              unsigned char* __restrict__ y2b) {
  int idx = blockIdx.x * blockDim.x + threadIdx.x;
  if (idx >= 1176 * T_BINS) return;
  int t = idx / 1176, n2 = idx - t * 1176;
  int c = n2 / 196, r = n2 % 196, i = r / 14, j = r % 14;
  const unsigned char* b = s1b + (size_t)t * 4704 + c * 784 + (2 * i) * 28 + 2 * j;
  y2b[idx] = (unsigned char)((int)b[0] + (int)b[1] + (int)b[28] + (int)b[29]);
}

// ---------------- chunked fused PSP(IIR) + spike scan -----------------------
template <typename Tin, typename Tout>
__global__ __launch_bounds__(256) void k_psp_scan_chunk(
    const Tin* __restrict__ z, Tout* __restrict__ sout, int N,
    long strideT, long strideN, const double* __restrict__ H_g,
    double A1, double A2, double B1, double C0, double C1, double xscale) {
  __shared__ double Hs[102];
  for (int k = threadIdx.x; k < 102; k += 256) Hs[k] = H_g[k];
  __syncthreads();
  int idx = blockIdx.x * blockDim.x + threadIdx.x;
  if (idx >= NCHK * N) return;
  int chunk = idx / N, n = idx - chunk * N;
  int t0 = chunk * CHK;
  int ts = (chunk == 0) ? 0 : t0 - WUP;
  const Tin* zn = z + n;

  // exact IIR init: accA=p[ts], accB=p[ts-1] (100-tap FIR, 10-deep pipe)
  double accA = 0.0, accB = 0.0;
  float fA[10], fB[10];
#define LOADF(BUF, J0)                                               \
  { _Pragma("unroll")                                                \
    for (int q_ = 0; q_ < 10; ++q_)                                  \
      BUF[q_] = (float)zn[(long)(ts - 1 - ((J0) + q_)) * (long)N]; }
#define FMA10(BUF, J0)                                               \
  { _Pragma("unroll")                                                \
    for (int q_ = 0; q_ < 10; ++q_) {                                \
      double v_ = (double)BUF[q_];                                   \
      accA += Hs[(J0) + q_ + 1] * v_;                                \
      accB += Hs[(J0) + q_] * v_;                                    \
    } }
  LOADF(fA, 0)
  for (int q = 0; q < 100; q += 20) {
    LOADF(fB, q + 10)
    FMA10(fA, q)
    LOADF(fA, q + 20)                  // q=80: overshoot, in-bounds, unused
    FMA10(fB, q + 10)
  }
#undef LOADF
#undef FMA10
  double pp1 = accA * xscale;          // p[ts]
  double pp2 = accB * xscale;          // p[ts-1]
  double xm100 = (double)(float)zn[(long)(ts - 100) * (long)N];
  double u = pp1, e1 = 0.0, e2 = 0.0;  // refractory speculated zero

  float cA[8], cB[8], lA[8], lB[8];
  size_t oa = (size_t)n * (size_t)strideN + (size_t)t0 * (size_t)strideT;
  int nwg = (t0 - ts) >> 3;            // 0 or 8 warmup groups
  int ngrp = nwg + CHK / 8;            // 8 or 16 (even)
#define PREF8(CBUF, LBUF, TB)                                        \
  { long tb_ = (long)(TB);                                           \
    _Pragma("unroll")                                                \
    for (int j_ = 0; j_ < 8; ++j_) {                                 \
      CBUF[j_] = (float)zn[(tb_ + j_) * (long)N];                    \
      LBUF[j_] = (float)zn[(tb_ + j_ - 99) * (long)N];               \
    } }
#define PROC8(CBUF, LBUF, DOSTORE)                                   \
  { _Pragma("unroll")                                                \
    for (int j_ = 0; j_ < 8; ++j_) {                                 \
      double s = (u >= 1.0) ? 1.0 : 0.0;                             \
      if (DOSTORE) { sout[oa] = (Tout)s; oa += (size_t)strideT; }    \
      double xt = (double)CBUF[j_], x99 = (double)LBUF[j_];          \
      double pn = A1 * pp1 - A2 * pp2 + B1 * xt - C0 * x99           \
                  + C1 * xm100;                                      \
      xm100 = x99;                                                   \
      u = pn - 2.0 * ((e1 + e2) + s);                                \
      double t1 = e1 + s;                                            \
      e2 = AEXP * (e2 + t1); e1 = AEXP * t1;                         \
      pp2 = pp1; pp1 = pn;                                           \
    } }
  PREF8(cA, lA, ts)
  for (int g = 0; g < ngrp; g += 2) {
    PREF8(cB, lB, ts + (g + 1) * 8)
    PROC8(cA, lA, g >= nwg)
    PREF8(cA, lA, ts + (g + 2) * 8)    // last iter overshoots into slack
    PROC8(cB, lB, g + 1 >= nwg)
  }
#undef PREF8
#undef PROC8
}

// ---------------- conv2: register-row-blocked, thread=(o,i) -----------------
__global__ __launch_bounds__(192) void k_conv2(const unsigned char* __restrict__ s2b,
                                               const float* __restrict__ W,
                                               float* __restrict__ z3) {
  __shared__ float ls[1176];
  __shared__ float lw[2400];
  int t = blockIdx.x;
  for (int i = threadIdx.x; i < 1176; i += 192)
    ls[i] = (float)s2b[(size_t)t * 1176 + i];
  for (int i = threadIdx.x; i < 2400; i += 192) lw[i] = W[i];
  __syncthreads();
  int tid = threadIdx.x;
  if (tid >= 160) return;
  int o = tid / 10, i = tid - o * 10;
  double acc[10];
#pragma unroll
  for (int j = 0; j < 10; ++j) acc[j] = 0.0;
  for (int ci = 0; ci < 6; ++ci)
#pragma unroll
    for (int ky = 0; ky < 5; ++ky) {
      const float* lr = &ls[ci * 196 + (i + ky) * 14];
      const float* wr = &lw[((o * 6 + ci) * 5 + ky) * 5];
      double r[14], w[5];
#pragma unroll
      for (int q = 0; q < 14; ++q) r[q] = (double)lr[q];
#pragma unroll
      for (int q = 0; q < 5; ++q) w[q] = (double)wr[q];
#pragma unroll
      for (int j = 0; j < 10; ++j)
        acc[j] += r[j] * w[0] + r[j + 1] * w[1] + r[j + 2] * w[2] +
                  r[j + 3] * w[3] + r[j + 4] * w[4];
    }
  float* zr = z3 + (size_t)t * 1600 + o * 100 + i * 10;
#pragma unroll
  for (int j = 0; j < 10; ++j) zr[j] = (float)acc[j];
}

// ---------------- dense1 bf16-limb MFMA (R9 kernel + XCD-pinned panels) -----
// 512 blocks: xcd=bid&7, ct=xcd&3 (one 1.5MB B-panel per XCD L2),
// bm=(bid>>3)|((xcd>>2)<<6) in 0..127 (16-row tile). 4 waves split K
// {13,13,12,12}; LDS f64 reduce; wave 0 writes z4. A-fragments from bytes.
__global__ __launch_bounds__(256) void k_mfma_dense1(
    const unsigned char* __restrict__ s3b, const unsigned short* __restrict__ BL,
    float* __restrict__ z4) {
  __shared__ double red[4][64][20];     // 40,960 B
  int bid = blockIdx.x;
  int xcd = bid & 7;
  int ct = xcd & 3;
  int bm = (bid >> 3) | ((xcd >> 2) << 6);     // 0..127
  int col0 = ct * 80;
  int w = threadIdx.x >> 6, lane = threadIdx.x & 63;
  int r = lane & 15, g = lane >> 4;
  int row = bm * 16 + r;
  int ks0 = (w <= 2) ? w * 13 : 38;
  int cnt = (w < 2) ? 13 : 12;

  // A fragments: k = (ks0+ks)*32 + g*8 + jj  (bf16 1.0/0.0)
  s16x8 a[13];
  const unsigned char* ab = s3b + (size_t)row * 1600 + ks0 * 32 + g * 8;
#pragma unroll
  for (int ks = 0; ks < 13; ++ks) {    // a[12] unused when cnt==12 (in-bounds)
    unsigned long long bits = *(const unsigned long long*)(ab + ks * 32);
    u16x8 f;
#pragma unroll
    for (int jj = 0; jj < 8; ++jj)
      f[jj] = ((bits >> (8 * jj)) & 1ULL) ? (unsigned short)0x3F80
                                          : (unsigned short)0;
    a[ks] = (s16x8)f;
  }

  double za[5][4];
#pragma unroll
  for (int nt = 0; nt < 5; ++nt)
#pragma unroll
    for (int q = 0; q < 4; ++q) za[nt][q] = 0.0;
  double scale = 1.0;
  for (int j = 0; j < 6; ++j) {
    f32x4 C[5];
#pragma unroll
    for (int nt = 0; nt < 5; ++nt) C[nt] = (f32x4){0.f, 0.f, 0.f, 0.f};
    for (int ks = 0; ks < cnt; ++ks) {
      const u16x8* bb =
          (const u16x8*)BL + ((size_t)((j * 50 + ks0 + ks) * 320 + col0 + r)) * 4 + g;
#pragma unroll
      for (int nt = 0; nt < 5; ++nt)
        C[nt] = __builtin_amdgcn_mfma_f32_16x16x32_bf16(
            a[ks], (s16x8)bb[nt * 64], C[nt], 0, 0, 0);
    }
#pragma unroll
    for (int nt = 0; nt < 5; ++nt)
#pragma unroll
      for (int q = 0; q < 4; ++q) za[nt][q] += scale * (double)C[nt][q];
    scale *= 256.0;
  }

#pragma unroll
  for (int nt = 0; nt < 5; ++nt)
#pragma unroll
    for (int q = 0; q < 4; ++q) red[w][lane][nt * 4 + q] = za[nt][q];
  __syncthreads();
  if (w == 0) {
#pragma unroll
    for (int nt = 0; nt < 5; ++nt) {
      int col = col0 + nt * 16 + r;
      if (col < 300) {
#pragma unroll
        for (int q = 0; q < 4; ++q) {
          int i = nt * 4 + q;
          double v = (red[0][lane][i] + red[1][lane][i]) +
                     (red[2][lane][i] + red[3][lane][i]);
          z4[(size_t)(bm * 16 + g * 4 + q) * 300 + col] =
              (float)(v * (1.0 / FIXS));
        }
      }
    }
  }
}

// ---------------- sparse dense: one output per lane -------------------------
template <int NIN, int NOUT, int BLK>
__global__ __launch_bounds__(BLK) void k_dense_sparse(
    const unsigned char* __restrict__ s, const float* __restrict__ WT,
    float* __restrict__ z) {
  constexpr int NCH = (NIN + BLK - 1) / BLK;
  constexpr int NW = BLK / 64;
  __shared__ __align__(16) int list[NIN];
  __shared__ int wcnt[NCH][NW];
  int t = blockIdx.x;
  const unsigned char* srow = s + (size_t)t * NIN;
  int tid = threadIdx.x, lane = tid & 63, wv = tid >> 6;
  unsigned long long msave[NCH];
  bool asave[NCH];
#pragma unroll
  for (int ci = 0; ci < NCH; ++ci) {
    int c = ci * BLK + tid;
    bool a = (c < NIN) && (srow[c] != 0);
    unsigned long long m = __ballot(a);
    msave[ci] = m; asave[ci] = a;
    if (lane == 0) wcnt[ci][wv] = __popcll(m);
  }
  __syncthreads();
  int nact = 0;
#pragma unroll
  for (int ci = 0; ci < NCH; ++ci) {
    int off = nact;
    for (int w = 0; w < wv; ++w) off += wcnt[ci][w];
    if (asave[ci])
      list[off + __popcll(msave[ci] & ((1ULL << lane) - 1))] = ci * BLK + tid;
    for (int w = 0; w < NW; ++w) nact += wcnt[ci][w];
  }
  __syncthreads();
  if (tid >= NOUT) return;
  const float* col = WT + tid;
  double a0 = 0.0, a1 = 0.0, a2 = 0.0, a3 = 0.0;
  int k = 0, nact4 = nact & ~3;
  for (; k < nact4; k += 4) {
    int4 l4 = *(const int4*)&list[k];
    a0 += (double)col[(size_t)l4.x * NOUT];
    a1 += (double)col[(size_t)l4.y * NOUT];
    a2 += (double)col[(size_t)l4.z * NOUT];
    a3 += (double)col[(size_t)l4.w * NOUT];
  }
  for (; k < nact; ++k) a0 += (double)col[(size_t)list[k] * NOUT];
  z[(size_t)t * NOUT + tid] = (float)((a0 + a1) + (a2 + a3));
}

// ---------------- launch ----------------------------------------------------
extern "C" void kernel_launch(void* const* d_in, const int* in_sizes, int n_in,
                              void* d_out, int out_size, void* d_ws, size_t ws_size,
                              hipStream_t stream) {
  const float* x   = (const float*)d_in[0];
  const float* Wc1 = (const float*)d_in[1];
  const float* Wc2 = (const float*)d_in[2];
  const float* Wf1 = (const float*)d_in[3];
  const float* Wf2 = (const float*)d_in[4];
  const float* Wf3 = (const float*)d_in[5];
  float* out = (float*)d_out;
  char* ws = (char*)d_ws;

  // Workspace (~39.3 MB). Zeroed pads below zA / y2b serve FIR/IIR negative-
  // row reads; slack absorbs prefetch overshoot (values unused). z4/z5/z6
  // reuse zA (z3 dead by then).
  double* Scum = (double*)(ws + 0);                   // double[100]
  double* Htab = (double*)(ws + 2048);                // double[102]
  float*  c1   = (float*)(ws + 4096);                 // float[4704]
  const size_t PADZ = 65536;                          // 655360 B zeros
  const size_t ZA   = PADZ + 655360;                  // 720896
  const size_t PADY = ZA + 13107200 + 262144;         // 14090240 (131072 zeros)
  const size_t Y2B  = PADY + 131072;                  // 14221312
  const size_t S1B  = Y2B + 2408448 + 65536;          // 16695296
  const size_t S2B  = S1B + 9633792;                  // 26329088
  const size_t S3B  = S2B + 2408448;                  // 28737536
  const size_t S4B  = S3B + 3276800;                  // 32014336
  const size_t S5B  = S4B + 614400;                   // 32628736
  const size_t WB   = S5B + 307200;                   // 32935936 WT2
  const size_t WC   = WB + 180000;                    // 33115936 WT3
  const size_t BLa  = 33122000;                       // BL: 6,144,000 (16-al.)
  float* zA = (float*)(ws + ZA);
  unsigned char* y2b = (unsigned char*)(ws + Y2B);
  unsigned char* s1b = (unsigned char*)(ws + S1B);
  unsigned char* s2b = (unsigned char*)(ws + S2B);
  unsigned char* s3b = (unsigned char*)(ws + S3B);
  unsigned char* s4b = (unsigned char*)(ws + S4B);
  unsigned char* s5b = (unsigned char*)(ws + S5B);
  float* WT2 = (float*)(ws + WB);
  float* WT3 = (float*)(ws + WC);
  unsigned short* BLp = (unsigned short*)(ws + BLa);

  // IIR coefficients (host, double): h[k] = c*k*b^k, truncated at K=100.
  double b = exp(-0.1), c = 0.1 * exp(1.0);
  double A1 = 2.0 * b, A2 = b * b;
  double B1 = c * b;
  double C0 = 100.0 * c * pow(b, 100.0);
  double C1 = 99.0 * c * pow(b, 101.0);
  double sc = (double)1.1f;                  // pool weight, exact fp32 value

  hipMemsetAsync(ws + PADZ, 0, 655360, stream);
  hipMemsetAsync(ws + PADY, 0, 131072, stream);
  k_prep<<<452, 256, 0, stream>>>(x, Wc1, Wf1, Wf2, Wf3, c1, Scum, Htab,
                                  WT2, WT3, BLp);
  k_scan1_chunk<<<NCHK * 4704 / 256, 256, 0, stream>>>(c1, Scum, s1b);
  k_pool<<<(1176 * T_BINS) / 256, 256, 0, stream>>>(s1b, y2b);
  k_psp_scan_chunk<unsigned char, unsigned char>
      <<<(NCHK * 1176 + 255) / 256, 256, 0, stream>>>(
      y2b, s2b, 1176, 1176L, 1L, Htab, A1, A2, B1 * sc, C0 * sc, C1 * sc, sc);
  k_conv2<<<T_BINS, 192, 0, stream>>>(s2b, Wc2, zA);
  k_psp_scan_chunk<float, unsigned char>
      <<<(NCHK * 1600 + 255) / 256, 256, 0, stream>>>(
      zA, s3b, 1600, 1600L, 1L, Htab, A1, A2, B1, C0, C1, 1.0);
  k_mfma_dense1<<<512, 256, 0, stream>>>(s3b, BLp, zA);
  k_psp_scan_chunk<float, unsigned char>
      <<<(NCHK * 300 + 255) / 256, 256, 0, stream>>>(
      zA, s4b, 300, 300L, 1L, Htab, A1, A2, B1, C0, C1, 1.0);
  k_dense_sparse<300, 150, 192><<<T_BINS, 192, 0, stream>>>(s4b, WT2, zA);
  k_psp_scan_chunk<float, unsigned char>
      <<<(NCHK * 150 + 255) / 256, 256, 0, stream>>>(
      zA, s5b, 150, 150L, 1L, Htab, A1, A2, B1, C0, C1, 1.0);
  k_dense_sparse<150, 10, 64><<<T_BINS, 64, 0, stream>>>(s5b, WT3, zA);
  k_psp_scan_chunk<float, float><<<2, 256, 0, stream>>>(
      zA, out, 10, 1L, 2048L, Htab, A1, A2, B1, C0, C1, 1.0);

  (void)in_sizes; (void)n_in; (void)out_size; (void)ws_size;
}

// Round 13
// 240.463 us; speedup vs baseline: 1.9276x; 1.1223x over previous
//
#include <hip/hip_runtime.h>
#include <math.h>

// SLAYER SNN forward, 6 layers, T=2048.
// Policy: compute near the TRUE value (error << reference's own fp32 noise
// ~1e-5) so binary spike decisions match the golden fp32 reference exactly.
//
// PSP = exact 2nd-order IIR of the truncated SRM kernel; refractory = 2-state
// recurrence; time-chunked speculative scan (32 chunks x 64 steps, 64-step
// warmup; init error decays e^-1/step -- proven R5-R12).
//
// DENSE1 (1600->300) as an EXACT fixed-point bf16 MFMA GEMM (R7/R9-proven):
//   w_fixed = round(w*2^45) = sum_{j<6} d_j 256^j, d_j signed 8-bit digits.
//   Digits and 0/1 spikes are exact in bf16; mfma_f32_16x16x32_bf16
//   accumulates integer partial sums < 2^24 -> EXACT in f32 C. Limb combine
//   in f64 (each term integer x 2^(8j), exact).
// R13 = R12 minus the scratch spill: (a) f64 limb accumulator moved to LDS
//   (red[4][64][21], pad 21 -> f64 4-way bank floor), RMW per limb;
//   (b) A-spike words reloaded per (j,ks) from L1 instead of hoisting 13
//   fragments. Live VGPR state ~50 -> no spill, B-loads pipeline.

#define T_BINS 2048
#define K_SRM  100
#define AEXP   0.36787944117144233   // e^-1
#define CHK    64                    // chunk output length
#define WUP    64                    // refractory warmup length (proven)
#define NCHK   (T_BINS / CHK)        // 32
#define FIXS   35184372088832.0      // 2^45

typedef __attribute__((ext_vector_type(8))) short          s16x8;
typedef __attribute__((ext_vector_type(8))) unsigned short u16x8;
typedef __attribute__((ext_vector_type(4))) float          f32x4;

// ---------------- fused prep: conv1 + packB(bf16 limbs) + transposes + init -
__global__ __launch_bounds__(256) void k_prep(
    const float* __restrict__ x, const float* __restrict__ Wc1,
    const float* __restrict__ Wf1, const float* __restrict__ Wf2,
    const float* __restrict__ Wf3, float* __restrict__ c1,
    double* __restrict__ Scum, double* __restrict__ H,
    float* __restrict__ WT2, float* __restrict__ WT3,
    unsigned short* __restrict__ BL) {
  int b = blockIdx.x, tid = threadIdx.x;
  if (b < 19) {                         // ---- conv1 -> c1[4704]
    int idx = b * 256 + tid;
    if (idx >= 4704) return;
    int o = idx / 784, r = idx % 784, i = r / 28, j = r % 28;
    double acc = 0.0;
    for (int ci = 0; ci < 3; ++ci)
      for (int ky = 0; ky < 5; ++ky) {
        const float* xr = x + ci * 1024 + (i + ky) * 32 + j;
        const float* wr = Wc1 + ((o * 3 + ci) * 5 + ky) * 5;
#pragma unroll
        for (int kx = 0; kx < 5; ++kx)
          acc += (double)xr[kx] * (double)wr[kx];
      }
    c1[idx] = (float)acc;
  } else if (b < 269) {                 // ---- packB: 6 bf16 digit limbs
    int idx = (b - 19) * 256 + tid;     // 50 ks x 320 n x 4 g = 64000
    if (idx >= 64000) return;
    int g = idx & 3, rest = idx >> 2;
    int n = rest % 320, ks = rest / 320;
    u16x8 out[6];
#pragma unroll
    for (int j = 0; j < 6; ++j)
#pragma unroll
      for (int jj = 0; jj < 8; ++jj) out[j][jj] = 0;
    if (n < 300) {
      const float* wr = Wf1 + (size_t)n * 1600 + ks * 32 + g * 8;
#pragma unroll
      for (int jj = 0; jj < 8; ++jj) {
        long long v = llrint((double)wr[jj] * FIXS);
#pragma unroll
        for (int j = 0; j < 6; ++j) {
          int d = (int)(signed char)(v & 0xFF);
          v = (v - d) >> 8;
          float fd = (float)d;               // exact; bf16 truncation exact
          unsigned int fb = __float_as_uint(fd);
          out[j][jj] = (unsigned short)(fb >> 16);
        }
      }
    }
#pragma unroll
    for (int j = 0; j < 6; ++j)
      ((u16x8*)BL)[((j * 50 + ks) * 320 + n) * 4 + g] = out[j];
  } else if (b < 451) {                 // ---- WT2 / WT3 transposes
    int idx = (b - 269) * 256 + tid;
    if (idx < 45000) {
      int c = idx / 150, o = idx - c * 150;
      WT2[idx] = Wf2[o * 300 + c];
    } else if (idx < 46500) {
      int j = idx - 45000, c = j / 10, o = j - c * 10;
      WT3[j] = Wf3[o * 150 + c];
    }
  } else {                              // ---- init tables
    if (tid == 0) {
      double acc = 0.0;
      for (int k = 0; k < K_SRM; ++k) {
        double tk = (double)k;
        double h = (tk * 0.1) * exp(1.0 - tk * 0.1);
        H[k] = h; acc += h; Scum[k] = acc;
      }
      H[100] = 0.0; H[101] = 0.0;
    }
  }
}

// ---------------- layer1 chunked scan: p1[t] = c1*Scum[t] -------------------
__global__ __launch_bounds__(256) void k_scan1_chunk(
    const float* __restrict__ c1, const double* __restrict__ Scum_g,
    unsigned char* __restrict__ s1b) {
  __shared__ double Sc[K_SRM];
  for (int k = threadIdx.x; k < K_SRM; k += 256) Sc[k] = Scum_g[k];
  __syncthreads();
  int idx = blockIdx.x * 256 + threadIdx.x;
  int chunk = idx / 4704, n = idx - chunk * 4704;
  int t0 = chunk * CHK;
  int ts = (chunk == 0) ? 0 : t0 - WUP;
  double w = (double)c1[n];
  double e1 = 0.0, e2 = 0.0;
  double u = w * Sc[ts < (K_SRM - 1) ? ts : (K_SRM - 1)];
  unsigned char* outp = s1b + n;
  for (int t = ts; t < t0; ++t) {       // warmup, no store
    double s = (u >= 1.0) ? 1.0 : 0.0;
    int si = t + 1 < (K_SRM - 1) ? t + 1 : (K_SRM - 1);
    u = w * Sc[si] - 2.0 * ((e1 + e2) + s);
    double t1 = e1 + s;
    e2 = AEXP * (e2 + t1); e1 = AEXP * t1;
  }
#pragma unroll 8
  for (int t = t0; t < t0 + CHK; ++t) { // output
    double s = (u >= 1.0) ? 1.0 : 0.0;
    outp[(size_t)t * 4704] = (unsigned char)s;
    int si = t + 1 < (K_SRM - 1) ? t + 1 : (K_SRM - 1);
    u = w * Sc[si] - 2.0 * ((e1 + e2) + s);
    double t1 = e1 + s;
    e2 = AEXP * (e2 + t1); e1 = AEXP * t1;
  }
}

// ---------------- pool: 2x2 spike count -> y2b[t][1176] bytes ---------------
__global__ __launch_bounds__(256) void k_pool(const unsigned char* __restrict__ s1b,
                                              unsigned char* __restrict__ y2b) {
  int idx = blockIdx.x * blockDim.x + threadIdx.x;
  if (idx >= 1176 * T_BINS) return;
  int t = idx / 1176, n2 = idx - t * 1176;
  int c = n2 / 196, r = n2 % 196, i = r / 14, j = r % 14;
  const unsigned char* b = s1b + (size_t)t * 4704 + c * 784 + (2 * i) * 28 + 2 * j;
  y2b[idx] = (unsigned char)((int)b[0] + (int)b[1] + (int)b[28] + (int)b[29]);
}

// ---------------- chunked fused PSP(IIR) + spike scan -----------------------
template <typename Tin, typename Tout>
__global__ __launch_bounds__(256) void k_psp_scan_chunk(
    const Tin* __restrict__ z, Tout* __restrict__ sout, int N,
    long strideT, long strideN, const double* __restrict__ H_g,
    double A1, double A2, double B1, double C0, double C1, double xscale) {
  __shared__ double Hs[102];
  for (int k = threadIdx.x; k < 102; k += 256) Hs[k] = H_g[k];
  __syncthreads();
  int idx = blockIdx.x * blockDim.x + threadIdx.x;
  if (idx >= NCHK * N) return;
  int chunk = idx / N, n = idx - chunk * N;
  int t0 = chunk * CHK;
  int ts = (chunk == 0) ? 0 : t0 - WUP;
  const Tin* zn = z + n;

  // exact IIR init: accA=p[ts], accB=p[ts-1] (100-tap FIR, 10-deep pipe)
  double accA = 0.0, accB = 0.0;
  float fA[10], fB[10];
#define LOADF(BUF, J0)                                               \
  { _Pragma("unroll")                                                \
    for (int q_ = 0; q_ < 10; ++q_)                                  \
      BUF[q_] = (float)zn[(long)(ts - 1 - ((J0) + q_)) * (long)N]; }
#define FMA10(BUF, J0)                                               \
  { _Pragma("unroll")                                                \
    for (int q_ = 0; q_ < 10; ++q_) {                                \
      double v_ = (double)BUF[q_];                                   \
      accA += Hs[(J0) + q_ + 1] * v_;                                \
      accB += Hs[(J0) + q_] * v_;                                    \
    } }
  LOADF(fA, 0)
  for (int q = 0; q < 100; q += 20) {
    LOADF(fB, q + 10)
    FMA10(fA, q)
    LOADF(fA, q + 20)                  // q=80: overshoot, in-bounds, unused
    FMA10(fB, q + 10)
  }
#undef LOADF
#undef FMA10
  double pp1 = accA * xscale;          // p[ts]
  double pp2 = accB * xscale;          // p[ts-1]
  double xm100 = (double)(float)zn[(long)(ts - 100) * (long)N];
  double u = pp1, e1 = 0.0, e2 = 0.0;  // refractory speculated zero

  float cA[8], cB[8], lA[8], lB[8];
  size_t oa = (size_t)n * (size_t)strideN + (size_t)t0 * (size_t)strideT;
  int nwg = (t0 - ts) >> 3;            // 0 or 8 warmup groups
  int ngrp = nwg + CHK / 8;            // 8 or 16 (even)
#define PREF8(CBUF, LBUF, TB)                                        \
  { long tb_ = (long)(TB);                                           \
    _Pragma("unroll")                                                \
    for (int j_ = 0; j_ < 8; ++j_) {                                 \
      CBUF[j_] = (float)zn[(tb_ + j_) * (long)N];                    \
      LBUF[j_] = (float)zn[(tb_ + j_ - 99) * (long)N];               \
    } }
#define PROC8(CBUF, LBUF, DOSTORE)                                   \
  { _Pragma("unroll")                                                \
    for (int j_ = 0; j_ < 8; ++j_) {                                 \
      double s = (u >= 1.0) ? 1.0 : 0.0;                             \
      if (DOSTORE) { sout[oa] = (Tout)s; oa += (size_t)strideT; }    \
      double xt = (double)CBUF[j_], x99 = (double)LBUF[j_];          \
      double pn = A1 * pp1 - A2 * pp2 + B1 * xt - C0 * x99           \
                  + C1 * xm100;                                      \
      xm100 = x99;                                                   \
      u = pn - 2.0 * ((e1 + e2) + s);                                \
      double t1 = e1 + s;                                            \
      e2 = AEXP * (e2 + t1); e1 = AEXP * t1;                         \
      pp2 = pp1; pp1 = pn;                                           \
    } }
  PREF8(cA, lA, ts)
  for (int g = 0; g < ngrp; g += 2) {
    PREF8(cB, lB, ts + (g + 1) * 8)
    PROC8(cA, lA, g >= nwg)
    PREF8(cA, lA, ts + (g + 2) * 8)    // last iter overshoots into slack
    PROC8(cB, lB, g + 1 >= nwg)
  }
#undef PREF8
#undef PROC8
}

// ---------------- conv2: register-row-blocked, thread=(o,i) -----------------
__global__ __launch_bounds__(192) void k_conv2(const unsigned char* __restrict__ s2b,
                                               const float* __restrict__ W,
                                               float* __restrict__ z3) {
  __shared__ float ls[1176];
  __shared__ float lw[2400];
  int t = blockIdx.x;
  for (int i = threadIdx.x; i < 1176; i += 192)
    ls[i] = (float)s2b[(size_t)t * 1176 + i];
  for (int i = threadIdx.x; i < 2400; i += 192) lw[i] = W[i];
  __syncthreads();
  int tid = threadIdx.x;
  if (tid >= 160) return;
  int o = tid / 10, i = tid - o * 10;
  double acc[10];
#pragma unroll
  for (int j = 0; j < 10; ++j) acc[j] = 0.0;
  for (int ci = 0; ci < 6; ++ci)
#pragma unroll
    for (int ky = 0; ky < 5; ++ky) {
      const float* lr = &ls[ci * 196 + (i + ky) * 14];
      const float* wr = &lw[((o * 6 + ci) * 5 + ky) * 5];
      double r[14], w[5];
#pragma unroll
      for (int q = 0; q < 14; ++q) r[q] = (double)lr[q];
#pragma unroll
      for (int q = 0; q < 5; ++q) w[q] = (double)wr[q];
#pragma unroll
      for (int j = 0; j < 10; ++j)
        acc[j] += r[j] * w[0] + r[j + 1] * w[1] + r[j + 2] * w[2] +
                  r[j + 3] * w[3] + r[j + 4] * w[4];
    }
  float* zr = z3 + (size_t)t * 1600 + o * 100 + i * 10;
#pragma unroll
  for (int j = 0; j < 10; ++j) zr[j] = (float)acc[j];
}

// ---------------- dense1 bf16-limb MFMA (R12 + LDS accumulator, no spill) ---
// 512 blocks: xcd=bid&7, ct=xcd&3 (one 1.5MB B-panel per XCD L2),
// bm=(bid>>3)|((xcd>>2)<<6) in 0..127 (16-row tile). 4 waves split K
// {13,13,12,12}. Limb accumulator lives in LDS (f64, pad 21 = 4-way floor);
// A spike-words reloaded per (j,ks) from L1 (13KB working set, no hoist).
__global__ __launch_bounds__(256) void k_mfma_dense1(
    const unsigned char* __restrict__ s3b, const unsigned short* __restrict__ BL,
    float* __restrict__ z4) {
  __shared__ double red[4][64][21];     // 43,008 B
  int bid = blockIdx.x;
  int xcd = bid & 7;
  int ct = xcd & 3;
  int bm = (bid >> 3) | ((xcd >> 2) << 6);     // 0..127
  int col0 = ct * 80;
  int w = threadIdx.x >> 6, lane = threadIdx.x & 63;
  int r = lane & 15, g = lane >> 4;
  int row = bm * 16 + r;
  int ks0 = (w <= 2) ? w * 13 : 38;
  int cnt = (w < 2) ? 13 : 12;
  const unsigned char* ab = s3b + (size_t)row * 1600 + ks0 * 32 + g * 8;

  // zero own accumulator slots (thread-private until the final barrier)
  double* myred = red[w][lane];
#pragma unroll
  for (int i = 0; i < 20; ++i) myred[i] = 0.0;

  double scale = 1.0;
  for (int j = 0; j < 6; ++j) {
    f32x4 C[5];
#pragma unroll
    for (int nt = 0; nt < 5; ++nt) C[nt] = (f32x4){0.f, 0.f, 0.f, 0.f};
    for (int ks = 0; ks < cnt; ++ks) {
      unsigned long long bits = *(const unsigned long long*)(ab + ks * 32);
      u16x8 f;
#pragma unroll
      for (int jj = 0; jj < 8; ++jj)
        f[jj] = ((bits >> (8 * jj)) & 1ULL) ? (unsigned short)0x3F80
                                            : (unsigned short)0;
      s16x8 a = (s16x8)f;
      const u16x8* bb =
          (const u16x8*)BL + ((size_t)((j * 50 + ks0 + ks) * 320 + col0 + r)) * 4 + g;
#pragma unroll
      for (int nt = 0; nt < 5; ++nt)
        C[nt] = __builtin_amdgcn_mfma_f32_16x16x32_bf16(
            a, (s16x8)bb[nt * 64], C[nt], 0, 0, 0);
    }
#pragma unroll
    for (int nt = 0; nt < 5; ++nt)
#pragma unroll
      for (int q = 0; q < 4; ++q)
        myred[nt * 4 + q] += scale * (double)C[nt][q];
    scale *= 256.0;
  }

  __syncthreads();
  if (w == 0) {
#pragma unroll
    for (int nt = 0; nt < 5; ++nt) {
      int col = col0 + nt * 16 + r;
      if (col < 300) {
#pragma unroll
        for (int q = 0; q < 4; ++q) {
          int i = nt * 4 + q;
          double v = (red[0][lane][i] + red[1][lane][i]) +
                     (red[2][lane][i] + red[3][lane][i]);
          z4[(size_t)(bm * 16 + g * 4 + q) * 300 + col] =
              (float)(v * (1.0 / FIXS));
        }
      }
    }
  }
}

// ---------------- sparse dense: one output per lane -------------------------
template <int NIN, int NOUT, int BLK>
__global__ __launch_bounds__(BLK) void k_dense_sparse(
    const unsigned char* __restrict__ s, const float* __restrict__ WT,
    float* __restrict__ z) {
  constexpr int NCH = (NIN + BLK - 1) / BLK;
  constexpr int NW = BLK / 64;
  __shared__ __align__(16) int list[NIN];
  __shared__ int wcnt[NCH][NW];
  int t = blockIdx.x;
  const unsigned char* srow = s + (size_t)t * NIN;
  int tid = threadIdx.x, lane = tid & 63, wv = tid >> 6;
  unsigned long long msave[NCH];
  bool asave[NCH];
#pragma unroll
  for (int ci = 0; ci < NCH; ++ci) {
    int c = ci * BLK + tid;
    bool a = (c < NIN) && (srow[c] != 0);
    unsigned long long m = __ballot(a);
    msave[ci] = m; asave[ci] = a;
    if (lane == 0) wcnt[ci][wv] = __popcll(m);
  }
  __syncthreads();
  int nact = 0;
#pragma unroll
  for (int ci = 0; ci < NCH; ++ci) {
    int off = nact;
    for (int w = 0; w < wv; ++w) off += wcnt[ci][w];
    if (asave[ci])
      list[off + __popcll(msave[ci] & ((1ULL << lane) - 1))] = ci * BLK + tid;
    for (int w = 0; w < NW; ++w) nact += wcnt[ci][w];
  }
  __syncthreads();
  if (tid >= NOUT) return;
  const float* col = WT + tid;
  double a0 = 0.0, a1 = 0.0, a2 = 0.0, a3 = 0.0;
  int k = 0, nact4 = nact & ~3;
  for (; k < nact4; k += 4) {
    int4 l4 = *(const int4*)&list[k];
    a0 += (double)col[(size_t)l4.x * NOUT];
    a1 += (double)col[(size_t)l4.y * NOUT];
    a2 += (double)col[(size_t)l4.z * NOUT];
    a3 += (double)col[(size_t)l4.w * NOUT];
  }
  for (; k < nact; ++k) a0 += (double)col[(size_t)list[k] * NOUT];
  z[(size_t)t * NOUT + tid] = (float)((a0 + a1) + (a2 + a3));
}

// ---------------- launch ----------------------------------------------------
extern "C" void kernel_launch(void* const* d_in, const int* in_sizes, int n_in,
                              void* d_out, int out_size, void* d_ws, size_t ws_size,
                              hipStream_t stream) {
  const float* x   = (const float*)d_in[0];
  const float* Wc1 = (const float*)d_in[1];
  const float* Wc2 = (const float*)d_in[2];
  const float* Wf1 = (const float*)d_in[3];
  const float* Wf2 = (const float*)d_in[4];
  const float* Wf3 = (const float*)d_in[5];
  float* out = (float*)d_out;
  char* ws = (char*)d_ws;

  // Workspace (~39.3 MB). Zeroed pads below zA / y2b serve FIR/IIR negative-
  // row reads; slack absorbs prefetch overshoot (values unused). z4/z5/z6
  // reuse zA (z3 dead by then).
  double* Scum = (double*)(ws + 0);                   // double[100]
  double* Htab = (double*)(ws + 2048);                // double[102]
  float*  c1   = (float*)(ws + 4096);                 // float[4704]
  const size_t PADZ = 65536;                          // 655360 B zeros
  const size_t ZA   = PADZ + 655360;                  // 720896
  const size_t PADY = ZA + 13107200 + 262144;         // 14090240 (131072 zeros)
  const size_t Y2B  = PADY + 131072;                  // 14221312
  const size_t S1B  = Y2B + 2408448 + 65536;          // 16695296
  const size_t S2B  = S1B + 9633792;                  // 26329088
  const size_t S3B  = S2B + 2408448;                  // 28737536
  const size_t S4B  = S3B + 3276800;                  // 32014336
  const size_t S5B  = S4B + 614400;                   // 32628736
  const size_t WB   = S5B + 307200;                   // 32935936 WT2
  const size_t WC   = WB + 180000;                    // 33115936 WT3
  const size_t BLa  = 33122000;                       // BL: 6,144,000 (16-al.)
  float* zA = (float*)(ws + ZA);
  unsigned char* y2b = (unsigned char*)(ws + Y2B);
  unsigned char* s1b = (unsigned char*)(ws + S1B);
  unsigned char* s2b = (unsigned char*)(ws + S2B);
  unsigned char* s3b = (unsigned char*)(ws + S3B);
  unsigned char* s4b = (unsigned char*)(ws + S4B);
  unsigned char* s5b = (unsigned char*)(ws + S5B);
  float* WT2 = (float*)(ws + WB);
  float* WT3 = (float*)(ws + WC);
  unsigned short* BLp = (unsigned short*)(ws + BLa);

  // IIR coefficients (host, double): h[k] = c*k*b^k, truncated at K=100.
  double b = exp(-0.1), c = 0.1 * exp(1.0);
  double A1 = 2.0 * b, A2 = b * b;
  double B1 = c * b;
  double C0 = 100.0 * c * pow(b, 100.0);
  double C1 = 99.0 * c * pow(b, 101.0);
  double sc = (double)1.1f;                  // pool weight, exact fp32 value

  hipMemsetAsync(ws + PADZ, 0, 655360, stream);
  hipMemsetAsync(ws + PADY, 0, 131072, stream);
  k_prep<<<452, 256, 0, stream>>>(x, Wc1, Wf1, Wf2, Wf3, c1, Scum, Htab,
                                  WT2, WT3, BLp);
  k_scan1_chunk<<<NCHK * 4704 / 256, 256, 0, stream>>>(c1, Scum, s1b);
  k_pool<<<(1176 * T_BINS) / 256, 256, 0, stream>>>(s1b, y2b);
  k_psp_scan_chunk<unsigned char, unsigned char>
      <<<(NCHK * 1176 + 255) / 256, 256, 0, stream>>>(
      y2b, s2b, 1176, 1176L, 1L, Htab, A1, A2, B1 * sc, C0 * sc, C1 * sc, sc);
  k_conv2<<<T_BINS, 192, 0, stream>>>(s2b, Wc2, zA);
  k_psp_scan_chunk<float, unsigned char>
      <<<(NCHK * 1600 + 255) / 256, 256, 0, stream>>>(
      zA, s3b, 1600, 1600L, 1L, Htab, A1, A2, B1, C0, C1, 1.0);
  k_mfma_dense1<<<512, 256, 0, stream>>>(s3b, BLp, zA);
  k_psp_scan_chunk<float, unsigned char>
      <<<(NCHK * 300 + 255) / 256, 256, 0, stream>>>(
      zA, s4b, 300, 300L, 1L, Htab, A1, A2, B1, C0, C1, 1.0);
  k_dense_sparse<300, 150, 192><<<T_BINS, 192, 0, stream>>>(s4b, WT2, zA);
  k_psp_scan_chunk<float, unsigned char>
      <<<(NCHK * 150 + 255) / 256, 256, 0, stream>>>(
      zA, s5b, 150, 150L, 1L, Htab, A1, A2, B1, C0, C1, 1.0);
  k_dense_sparse<150, 10, 64><<<T_BINS, 64, 0, stream>>>(s5b, WT3, zA);
  k_psp_scan_chunk<float, float><<<2, 256, 0, stream>>>(
      zA, out, 10, 1L, 2048L, Htab, A1, A2, B1, C0, C1, 1.0);

  (void)in_sizes; (void)n_in; (void)out_size; (void)ws_size;
}

// Round 14
// 237.448 us; speedup vs baseline: 1.9521x; 1.0127x over previous
//
#include <hip/hip_runtime.h>
#include <math.h>

// SLAYER SNN forward, 6 layers, T=2048.
// Policy: compute near the TRUE value (error << reference's own fp32 noise
// ~1e-5) so binary spike decisions match the golden fp32 reference exactly.
//
// PSP = exact 2nd-order IIR of the truncated SRM kernel; refractory = 2-state
// recurrence; time-chunked speculative scan (64 chunks x 32 steps, 48-step
// warmup -- WUP=48 proven R7; chunks with t0<WUP start at ts=0 EXACTLY).
//
// DENSE1 (1600->300) as an EXACT fixed-point bf16 MFMA GEMM (R7/R9-proven):
//   w_fixed = round(w*2^45) = sum_{j<6} d_j 256^j, d_j signed 8-bit digits.
//   Digits and 0/1 spikes are exact in bf16; mfma_f32_16x16x32_bf16
//   accumulates integer partial sums < 2^24 -> EXACT in f32 C. Limb combine
//   in f64 (each term integer x 2^(8j), exact).
// R14 = R13 + a[13] A-fragment hoist (R12's proven pattern; safe now that the
//   f64 accumulator lives in LDS -- live VGPR ~110, no spill). Loop body is
//   pure {5 B-loads -> 5 MFMAs}: compiler can pipeline across ks.

#define T_BINS 2048
#define K_SRM  100
#define AEXP   0.36787944117144233   // e^-1
#define CHK    32                    // chunk output length
#define WUP    48                    // refractory warmup length (proven R7)
#define NCHK   (T_BINS / CHK)        // 64
#define FIXS   35184372088832.0      // 2^45

typedef __attribute__((ext_vector_type(8))) short          s16x8;
typedef __attribute__((ext_vector_type(8))) unsigned short u16x8;
typedef __attribute__((ext_vector_type(4))) float          f32x4;

// ---------------- fused prep: conv1 + packB(bf16 limbs) + transposes + init -
__global__ __launch_bounds__(256) void k_prep(
    const float* __restrict__ x, const float* __restrict__ Wc1,
    const float* __restrict__ Wf1, const float* __restrict__ Wf2,
    const float* __restrict__ Wf3, float* __restrict__ c1,
    double* __restrict__ Scum, double* __restrict__ H,
    float* __restrict__ WT2, float* __restrict__ WT3,
    unsigned short* __restrict__ BL) {
  int b = blockIdx.x, tid = threadIdx.x;
  if (b < 19) {                         // ---- conv1 -> c1[4704]
    int idx = b * 256 + tid;
    if (idx >= 4704) return;
    int o = idx / 784, r = idx % 784, i = r / 28, j = r % 28;
    double acc = 0.0;
    for (int ci = 0; ci < 3; ++ci)
      for (int ky = 0; ky < 5; ++ky) {
        const float* xr = x + ci * 1024 + (i + ky) * 32 + j;
        const float* wr = Wc1 + ((o * 3 + ci) * 5 + ky) * 5;
#pragma unroll
        for (int kx = 0; kx < 5; ++kx)
          acc += (double)xr[kx] * (double)wr[kx];
      }
    c1[idx] = (float)acc;
  } else if (b < 269) {                 // ---- packB: 6 bf16 digit limbs
    int idx = (b - 19) * 256 + tid;     // 50 ks x 320 n x 4 g = 64000
    if (idx >= 64000) return;
    int g = idx & 3, rest = idx >> 2;
    int n = rest % 320, ks = rest / 320;
    u16x8 out[6];
#pragma unroll
    for (int j = 0; j < 6; ++j)
#pragma unroll
      for (int jj = 0; jj < 8; ++jj) out[j][jj] = 0;
    if (n < 300) {
      const float* wr = Wf1 + (size_t)n * 1600 + ks * 32 + g * 8;
#pragma unroll
      for (int jj = 0; jj < 8; ++jj) {
        long long v = llrint((double)wr[jj] * FIXS);
#pragma unroll
        for (int j = 0; j < 6; ++j) {
          int d = (int)(signed char)(v & 0xFF);
          v = (v - d) >> 8;
          float fd = (float)d;               // exact; bf16 truncation exact
          unsigned int fb = __float_as_uint(fd);
          out[j][jj] = (unsigned short)(fb >> 16);
        }
      }
    }
#pragma unroll
    for (int j = 0; j < 6; ++j)
      ((u16x8*)BL)[((j * 50 + ks) * 320 + n) * 4 + g] = out[j];
  } else if (b < 451) {                 // ---- WT2 / WT3 transposes
    int idx = (b - 269) * 256 + tid;
    if (idx < 45000) {
      int c = idx / 150, o = idx - c * 150;
      WT2[idx] = Wf2[o * 300 + c];
    } else if (idx < 46500) {
      int j = idx - 45000, c = j / 10, o = j - c * 10;
      WT3[j] = Wf3[o * 150 + c];
    }
  } else {                              // ---- init tables
    if (tid == 0) {
      double acc = 0.0;
      for (int k = 0; k < K_SRM; ++k) {
        double tk = (double)k;
        double h = (tk * 0.1) * exp(1.0 - tk * 0.1);
        H[k] = h; acc += h; Scum[k] = acc;
      }
      H[100] = 0.0; H[101] = 0.0;
    }
  }
}

// ---------------- layer1 chunked scan: p1[t] = c1*Scum[t] -------------------
__global__ __launch_bounds__(256) void k_scan1_chunk(
    const float* __restrict__ c1, const double* __restrict__ Scum_g,
    unsigned char* __restrict__ s1b) {
  __shared__ double Sc[K_SRM];
  for (int k = threadIdx.x; k < K_SRM; k += 256) Sc[k] = Scum_g[k];
  __syncthreads();
  int idx = blockIdx.x * 256 + threadIdx.x;
  int chunk = idx / 4704, n = idx - chunk * 4704;
  int t0 = chunk * CHK;
  int ts = t0 - WUP; if (ts < 0) ts = 0;   // ts==0 -> exact init
  double w = (double)c1[n];
  double e1 = 0.0, e2 = 0.0;
  double u = w * Sc[ts < (K_SRM - 1) ? ts : (K_SRM - 1)];
  unsigned char* outp = s1b + n;
  for (int t = ts; t < t0; ++t) {       // warmup, no store
    double s = (u >= 1.0) ? 1.0 : 0.0;
    int si = t + 1 < (K_SRM - 1) ? t + 1 : (K_SRM - 1);
    u = w * Sc[si] - 2.0 * ((e1 + e2) + s);
    double t1 = e1 + s;
    e2 = AEXP * (e2 + t1); e1 = AEXP * t1;
  }
#pragma unroll 8
  for (int t = t0; t < t0 + CHK; ++t) { // output
    double s = (u >= 1.0) ? 1.0 : 0.0;
    outp[(size_t)t * 4704] = (unsigned char)s;
    int si = t + 1 < (K_SRM - 1) ? t + 1 : (K_SRM - 1);
    u = w * Sc[si] - 2.0 * ((e1 + e2) + s);
    double t1 = e1 + s;
    e2 = AEXP * (e2 + t1); e1 = AEXP * t1;
  }
}

// ---------------- pool: 2x2 spike count -> y2b[t][1176] bytes ---------------
__global__ __launch_bounds__(256) void k_pool(const unsigned char* __restrict__ s1b,
                                              unsigned char* __restrict__ y2b) {
  int idx = blockIdx.x * blockDim.x + threadIdx.x;
  if (idx >= 1176 * T_BINS) return;
  int t = idx / 1176, n2 = idx - t * 1176;
  int c = n2 / 196, r = n2 % 196, i = r / 14, j = r % 14;
  const unsigned char* b = s1b + (size_t)t * 4704 + c * 784 + (2 * i) * 28 + 2 * j;
  y2b[idx] = (unsigned char)((int)b[0] + (int)b[1] + (int)b[28] + (int)b[29]);
}

// ---------------- chunked fused PSP(IIR) + spike scan -----------------------
template <typename Tin, typename Tout>
__global__ __launch_bounds__(256) void k_psp_scan_chunk(
    const Tin* __restrict__ z, Tout* __restrict__ sout, int N,
    long strideT, long strideN, const double* __restrict__ H_g,
    double A1, double A2, double B1, double C0, double C1, double xscale) {
  __shared__ double Hs[102];
  for (int k = threadIdx.x; k < 102; k += 256) Hs[k] = H_g[k];
  __syncthreads();
  int idx = blockIdx.x * blockDim.x + threadIdx.x;
  if (idx >= NCHK * N) return;
  int chunk = idx / N, n = idx - chunk * N;
  int t0 = chunk * CHK;
  int ts = t0 - WUP; if (ts < 0) ts = 0;   // ts==0 -> exact init
  const Tin* zn = z + n;

  // exact IIR init: accA=p[ts], accB=p[ts-1] (100-tap FIR, 10-deep pipe)
  double accA = 0.0, accB = 0.0;
  float fA[10], fB[10];
#define LOADF(BUF, J0)                                               \
  { _Pragma("unroll")                                                \
    for (int q_ = 0; q_ < 10; ++q_)                                  \
      BUF[q_] = (float)zn[(long)(ts - 1 - ((J0) + q_)) * (long)N]; }
#define FMA10(BUF, J0)                                               \
  { _Pragma("unroll")                                                \
    for (int q_ = 0; q_ < 10; ++q_) {                                \
      double v_ = (double)BUF[q_];                                   \
      accA += Hs[(J0) + q_ + 1] * v_;                                \
      accB += Hs[(J0) + q_] * v_;                                    \
    } }
  LOADF(fA, 0)
  for (int q = 0; q < 100; q += 20) {
    LOADF(fB, q + 10)
    FMA10(fA, q)
    LOADF(fA, q + 20)                  // q=80: overshoot, in-bounds, unused
    FMA10(fB, q + 10)
  }
#undef LOADF
#undef FMA10
  double pp1 = accA * xscale;          // p[ts]
  double pp2 = accB * xscale;          // p[ts-1]
  double xm100 = (double)(float)zn[(long)(ts - 100) * (long)N];
  double u = pp1, e1 = 0.0, e2 = 0.0;  // refractory zero (exact at ts==0)

  float cA[8], cB[8], lA[8], lB[8];
  size_t oa = (size_t)n * (size_t)strideN + (size_t)t0 * (size_t)strideT;
  int nwg = (t0 - ts) >> 3;            // 0, 4, or 6 warmup groups
  int ngrp = nwg + CHK / 8;            // 4, 8, or 10 (even)
#define PREF8(CBUF, LBUF, TB)                                        \
  { long tb_ = (long)(TB);                                           \
    _Pragma("unroll")                                                \
    for (int j_ = 0; j_ < 8; ++j_) {                                 \
      CBUF[j_] = (float)zn[(tb_ + j_) * (long)N];                    \
      LBUF[j_] = (float)zn[(tb_ + j_ - 99) * (long)N];               \
    } }
#define PROC8(CBUF, LBUF, DOSTORE)                                   \
  { _Pragma("unroll")                                                \
    for (int j_ = 0; j_ < 8; ++j_) {                                 \
      double s = (u >= 1.0) ? 1.0 : 0.0;                             \
      if (DOSTORE) { sout[oa] = (Tout)s; oa += (size_t)strideT; }    \
      double xt = (double)CBUF[j_], x99 = (double)LBUF[j_];          \
      double pn = A1 * pp1 - A2 * pp2 + B1 * xt - C0 * x99           \
                  + C1 * xm100;                                      \
      xm100 = x99;                                                   \
      u = pn - 2.0 * ((e1 + e2) + s);                                \
      double t1 = e1 + s;                                            \
      e2 = AEXP * (e2 + t1); e1 = AEXP * t1;                         \
      pp2 = pp1; pp1 = pn;                                           \
    } }
  PREF8(cA, lA, ts)
  for (int g = 0; g < ngrp; g += 2) {
    PREF8(cB, lB, ts + (g + 1) * 8)
    PROC8(cA, lA, g >= nwg)
    PREF8(cA, lA, ts + (g + 2) * 8)    // last iter overshoots into slack
    PROC8(cB, lB, g + 1 >= nwg)
  }
#undef PREF8
#undef PROC8
}

// ---------------- conv2: register-row-blocked, thread=(o,i) -----------------
__global__ __launch_bounds__(192) void k_conv2(const unsigned char* __restrict__ s2b,
                                               const float* __restrict__ W,
                                               float* __restrict__ z3) {
  __shared__ float ls[1176];
  __shared__ float lw[2400];
  int t = blockIdx.x;
  for (int i = threadIdx.x; i < 1176; i += 192)
    ls[i] = (float)s2b[(size_t)t * 1176 + i];
  for (int i = threadIdx.x; i < 2400; i += 192) lw[i] = W[i];
  __syncthreads();
  int tid = threadIdx.x;
  if (tid >= 160) return;
  int o = tid / 10, i = tid - o * 10;
  double acc[10];
#pragma unroll
  for (int j = 0; j < 10; ++j) acc[j] = 0.0;
  for (int ci = 0; ci < 6; ++ci)
#pragma unroll
    for (int ky = 0; ky < 5; ++ky) {
      const float* lr = &ls[ci * 196 + (i + ky) * 14];
      const float* wr = &lw[((o * 6 + ci) * 5 + ky) * 5];
      double r[14], w[5];
#pragma unroll
      for (int q = 0; q < 14; ++q) r[q] = (double)lr[q];
#pragma unroll
      for (int q = 0; q < 5; ++q) w[q] = (double)wr[q];
#pragma unroll
      for (int j = 0; j < 10; ++j)
        acc[j] += r[j] * w[0] + r[j + 1] * w[1] + r[j + 2] * w[2] +
                  r[j + 3] * w[3] + r[j + 4] * w[4];
    }
  float* zr = z3 + (size_t)t * 1600 + o * 100 + i * 10;
#pragma unroll
  for (int j = 0; j < 10; ++j) zr[j] = (float)acc[j];
}

// ---------------- dense1 bf16-limb MFMA (R13 + A-fragment hoist) ------------
// 512 blocks: xcd=bid&7, ct=xcd&3 (one 1.5MB B-panel per XCD L2),
// bm=(bid>>3)|((xcd>>2)<<6) in 0..127 (16-row tile). 4 waves split K
// {13,13,12,12}. f64 limb accumulator in LDS (pad 21); A-fragments hoisted
// into registers ONCE (R12 pattern) -> inner loop = pure B-load + MFMA.
__global__ __launch_bounds__(256) void k_mfma_dense1(
    const unsigned char* __restrict__ s3b, const unsigned short* __restrict__ BL,
    float* __restrict__ z4) {
  __shared__ double red[4][64][21];     // 43,008 B
  int bid = blockIdx.x;
  int xcd = bid & 7;
  int ct = xcd & 3;
  int bm = (bid >> 3) | ((xcd >> 2) << 6);     // 0..127
  int col0 = ct * 80;
  int w = threadIdx.x >> 6, lane = threadIdx.x & 63;
  int r = lane & 15, g = lane >> 4;
  int row = bm * 16 + r;
  int ks0 = (w <= 2) ? w * 13 : 38;
  int cnt = (w < 2) ? 13 : 12;
  const unsigned char* ab = s3b + (size_t)row * 1600 + ks0 * 32 + g * 8;

  // hoist A fragments: k = (ks0+ks)*32 + g*8 + jj  (bf16 1.0/0.0)
  s16x8 a[13];
#pragma unroll
  for (int ks = 0; ks < 13; ++ks) {    // a[12] unused when cnt==12 (in-bounds)
    unsigned long long bits = *(const unsigned long long*)(ab + ks * 32);
    u16x8 f;
#pragma unroll
    for (int jj = 0; jj < 8; ++jj)
      f[jj] = ((bits >> (8 * jj)) & 1ULL) ? (unsigned short)0x3F80
                                          : (unsigned short)0;
    a[ks] = (s16x8)f;
  }

  // zero own accumulator slots (thread-private until the final barrier)
  double* myred = red[w][lane];
#pragma unroll
  for (int i = 0; i < 20; ++i) myred[i] = 0.0;

  double scale = 1.0;
  for (int j = 0; j < 6; ++j) {
    f32x4 C[5];
#pragma unroll
    for (int nt = 0; nt < 5; ++nt) C[nt] = (f32x4){0.f, 0.f, 0.f, 0.f};
    for (int ks = 0; ks < cnt; ++ks) {
      const u16x8* bb =
          (const u16x8*)BL + ((size_t)((j * 50 + ks0 + ks) * 320 + col0 + r)) * 4 + g;
#pragma unroll
      for (int nt = 0; nt < 5; ++nt)
        C[nt] = __builtin_amdgcn_mfma_f32_16x16x32_bf16(
            a[ks], (s16x8)bb[nt * 64], C[nt], 0, 0, 0);
    }
#pragma unroll
    for (int nt = 0; nt < 5; ++nt)
#pragma unroll
      for (int q = 0; q < 4; ++q)
        myred[nt * 4 + q] += scale * (double)C[nt][q];
    scale *= 256.0;
  }

  __syncthreads();
  if (w == 0) {
#pragma unroll
    for (int nt = 0; nt < 5; ++nt) {
      int col = col0 + nt * 16 + r;
      if (col < 300) {
#pragma unroll
        for (int q = 0; q < 4; ++q) {
          int i = nt * 4 + q;
          double v = (red[0][lane][i] + red[1][lane][i]) +
                     (red[2][lane][i] + red[3][lane][i]);
          z4[(size_t)(bm * 16 + g * 4 + q) * 300 + col] =
              (float)(v * (1.0 / FIXS));
        }
      }
    }
  }
}

// ---------------- sparse dense: one output per lane -------------------------
template <int NIN, int NOUT, int BLK>
__global__ __launch_bounds__(BLK) void k_dense_sparse(
    const unsigned char* __restrict__ s, const float* __restrict__ WT,
    float* __restrict__ z) {
  constexpr int NCH = (NIN + BLK - 1) / BLK;
  constexpr int NW = BLK / 64;
  __shared__ __align__(16) int list[NIN];
  __shared__ int wcnt[NCH][NW];
  int t = blockIdx.x;
  const unsigned char* srow = s + (size_t)t * NIN;
  int tid = threadIdx.x, lane = tid & 63, wv = tid >> 6;
  unsigned long long msave[NCH];
  bool asave[NCH];
#pragma unroll
  for (int ci = 0; ci < NCH; ++ci) {
    int c = ci * BLK + tid;
    bool a = (c < NIN) && (srow[c] != 0);
    unsigned long long m = __ballot(a);
    msave[ci] = m; asave[ci] = a;
    if (lane == 0) wcnt[ci][wv] = __popcll(m);
  }
  __syncthreads();
  int nact = 0;
#pragma unroll
  for (int ci = 0; ci < NCH; ++ci) {
    int off = nact;
    for (int w = 0; w < wv; ++w) off += wcnt[ci][w];
    if (asave[ci])
      list[off + __popcll(msave[ci] & ((1ULL << lane) - 1))] = ci * BLK + tid;
    for (int w = 0; w < NW; ++w) nact += wcnt[ci][w];
  }
  __syncthreads();
  if (tid >= NOUT) return;
  const float* col = WT + tid;
  double a0 = 0.0, a1 = 0.0, a2 = 0.0, a3 = 0.0;
  int k = 0, nact4 = nact & ~3;
  for (; k < nact4; k += 4) {
    int4 l4 = *(const int4*)&list[k];
    a0 += (double)col[(size_t)l4.x * NOUT];
    a1 += (double)col[(size_t)l4.y * NOUT];
    a2 += (double)col[(size_t)l4.z * NOUT];
    a3 += (double)col[(size_t)l4.w * NOUT];
  }
  for (; k < nact; ++k) a0 += (double)col[(size_t)list[k] * NOUT];
  z[(size_t)t * NOUT + tid] = (float)((a0 + a1) + (a2 + a3));
}

// ---------------- launch ----------------------------------------------------
extern "C" void kernel_launch(void* const* d_in, const int* in_sizes, int n_in,
                              void* d_out, int out_size, void* d_ws, size_t ws_size,
                              hipStream_t stream) {
  const float* x   = (const float*)d_in[0];
  const float* Wc1 = (const float*)d_in[1];
  const float* Wc2 = (const float*)d_in[2];
  const float* Wf1 = (const float*)d_in[3];
  const float* Wf2 = (const float*)d_in[4];
  const float* Wf3 = (const float*)d_in[5];
  float* out = (float*)d_out;
  char* ws = (char*)d_ws;

  // Workspace (~39.3 MB). Zeroed pads below zA / y2b serve FIR/IIR negative-
  // row reads (nonzero-tap rows >= -99 in pad; deeper overshoot rows are
  // in-bounds, values unused). z4/z5/z6 reuse zA (z3 dead by then).
  double* Scum = (double*)(ws + 0);                   // double[100]
  double* Htab = (double*)(ws + 2048);                // double[102]
  float*  c1   = (float*)(ws + 4096);                 // float[4704]
  const size_t PADZ = 65536;                          // 655360 B zeros
  const size_t ZA   = PADZ + 655360;                  // 720896
  const size_t PADY = ZA + 13107200 + 262144;         // 14090240 (131072 zeros)
  const size_t Y2B  = PADY + 131072;                  // 14221312
  const size_t S1B  = Y2B + 2408448 + 65536;          // 16695296
  const size_t S2B  = S1B + 9633792;                  // 26329088
  const size_t S3B  = S2B + 2408448;                  // 28737536
  const size_t S4B  = S3B + 3276800;                  // 32014336
  const size_t S5B  = S4B + 614400;                   // 32628736
  const size_t WB   = S5B + 307200;                   // 32935936 WT2
  const size_t WC   = WB + 180000;                    // 33115936 WT3
  const size_t BLa  = 33122000;                       // BL: 6,144,000 (16-al.)
  float* zA = (float*)(ws + ZA);
  unsigned char* y2b = (unsigned char*)(ws + Y2B);
  unsigned char* s1b = (unsigned char*)(ws + S1B);
  unsigned char* s2b = (unsigned char*)(ws + S2B);
  unsigned char* s3b = (unsigned char*)(ws + S3B);
  unsigned char* s4b = (unsigned char*)(ws + S4B);
  unsigned char* s5b = (unsigned char*)(ws + S5B);
  float* WT2 = (float*)(ws + WB);
  float* WT3 = (float*)(ws + WC);
  unsigned short* BLp = (unsigned short*)(ws + BLa);

  // IIR coefficients (host, double): h[k] = c*k*b^k, truncated at K=100.
  double b = exp(-0.1), c = 0.1 * exp(1.0);
  double A1 = 2.0 * b, A2 = b * b;
  double B1 = c * b;
  double C0 = 100.0 * c * pow(b, 100.0);
  double C1 = 99.0 * c * pow(b, 101.0);
  double sc = (double)1.1f;                  // pool weight, exact fp32 value

  hipMemsetAsync(ws + PADZ, 0, 655360, stream);
  hipMemsetAsync(ws + PADY, 0, 131072, stream);
  k_prep<<<452, 256, 0, stream>>>(x, Wc1, Wf1, Wf2, Wf3, c1, Scum, Htab,
                                  WT2, WT3, BLp);
  k_scan1_chunk<<<NCHK * 4704 / 256, 256, 0, stream>>>(c1, Scum, s1b);
  k_pool<<<(1176 * T_BINS) / 256, 256, 0, stream>>>(s1b, y2b);
  k_psp_scan_chunk<unsigned char, unsigned char>
      <<<(NCHK * 1176 + 255) / 256, 256, 0, stream>>>(
      y2b, s2b, 1176, 1176L, 1L, Htab, A1, A2, B1 * sc, C0 * sc, C1 * sc, sc);
  k_conv2<<<T_BINS, 192, 0, stream>>>(s2b, Wc2, zA);
  k_psp_scan_chunk<float, unsigned char>
      <<<(NCHK * 1600 + 255) / 256, 256, 0, stream>>>(
      zA, s3b, 1600, 1600L, 1L, Htab, A1, A2, B1, C0, C1, 1.0);
  k_mfma_dense1<<<512, 256, 0, stream>>>(s3b, BLp, zA);
  k_psp_scan_chunk<float, unsigned char>
      <<<(NCHK * 300 + 255) / 256, 256, 0, stream>>>(
      zA, s4b, 300, 300L, 1L, Htab, A1, A2, B1, C0, C1, 1.0);
  k_dense_sparse<300, 150, 192><<<T_BINS, 192, 0, stream>>>(s4b, WT2, zA);
  k_psp_scan_chunk<float, unsigned char>
      <<<(NCHK * 150 + 255) / 256, 256, 0, stream>>>(
      zA, s5b, 150, 150L, 1L, Htab, A1, A2, B1, C0, C1, 1.0);
  k_dense_sparse<150, 10, 64><<<T_BINS, 64, 0, stream>>>(s5b, WT3, zA);
  k_psp_scan_chunk<float, float>
      <<<(NCHK * 10 + 255) / 256, 256, 0, stream>>>(
      zA, out, 10, 1L, 2048L, Htab, A1, A2, B1, C0, C1, 1.0);

  (void)in_sizes; (void)n_in; (void)out_size; (void)ws_size;
}